// Round 8
// baseline (446.886 us; speedup 1.0000x reference)
//
#include <hip/hip_runtime.h>
#include <hip/hip_bf16.h>
#include <math.h>

// ---------------- constants ----------------
#define BSZ      8
#define TPREF    6144
#define CIN      8
#define DMODEL   256
#define DINNER   512
#define DSTATE   32
#define NHEADS   8
#define HEADDIM  64
#define CONVDIM  576
#define DPROJ    1096
#define NTOK     512
#define NVIS     384     // unmasked tokens
#define TBWD     128     // bwd truncation (tokens 384..511 reversed)
#define MFWD     (BSZ * NTOK)      // 4096 rows
#define MBWD     (BSZ * TBWD)      // 1024 rows
#define MALL     (MFWD + MBWD)     // 5120 rows

typedef float f32x4 __attribute__((ext_vector_type(4)));
typedef __bf16 bf16x8 __attribute__((ext_vector_type(8)));

__device__ __forceinline__ float silu_f(float x) { return x / (1.f + expf(-x)); }

#define ASYNC16(gp, lp) \
    __builtin_amdgcn_global_load_lds((const __attribute__((address_space(1))) void*)(gp), \
                                     (__attribute__((address_space(3))) void*)(lp), 16, 0, 0)

// ---------------- generic bf16 MFMA GEMM (NT): C[m,n] = sum_k A[m,k]*Bt[n,k] ----------------
// flags: 2 = atomicAdd into fp32 C; 4 = silu(v+bias) + bf16 store; 8 = partial store at z*pstr
__global__ __launch_bounds__(256) void gemm_mfma(
    const __bf16* __restrict__ A, const __bf16* __restrict__ Bt,
    float* __restrict__ C, const float* __restrict__ bias,
    int N, int K, int ldc, int flags, long pstr) {
    __shared__ char sm[16384];
    int tid = threadIdx.x;
    int m0 = blockIdx.y * 128, n0 = blockIdx.x * 128;
    int klen = K / gridDim.z;
    int kbeg = blockIdx.z * klen;
    int w = tid >> 6, l = tid & 63;
    int wm = w >> 1, wn = w & 1;
    int lm = l & 15, q = l >> 4;

    f32x4 acc[4][4];
    #pragma unroll
    for (int i = 0; i < 4; i++)
        #pragma unroll
        for (int j = 0; j < 4; j++) acc[i][j] = (f32x4)0.f;

    for (int k0 = 0; k0 < klen; k0 += 32) {
        int kb = kbeg + k0;
        #pragma unroll
        for (int i = 0; i < 2; i++) {
            int s = i * 256 + tid;
            ASYNC16(A + (size_t)(m0 + (s >> 2)) * K + kb + (s & 3) * 8, sm + s * 16);
        }
        #pragma unroll
        for (int i = 0; i < 2; i++) {
            int s = i * 256 + tid;
            ASYNC16(Bt + (size_t)(n0 + (s >> 2)) * K + kb + (s & 3) * 8, sm + 8192 + s * 16);
        }
        __syncthreads();
        bf16x8 af[4], bfr[4];
        #pragma unroll
        for (int mf = 0; mf < 4; mf++)
            af[mf] = *(const bf16x8*)(sm + (wm * 64 + mf * 16 + lm) * 64 + q * 16);
        #pragma unroll
        for (int nf = 0; nf < 4; nf++)
            bfr[nf] = *(const bf16x8*)(sm + 8192 + (wn * 64 + nf * 16 + lm) * 64 + q * 16);
        #pragma unroll
        for (int mf = 0; mf < 4; mf++)
            #pragma unroll
            for (int nf = 0; nf < 4; nf++)
                acc[mf][nf] = __builtin_amdgcn_mfma_f32_16x16x32_bf16(af[mf], bfr[nf], acc[mf][nf], 0, 0, 0);
        __syncthreads();
    }

    #pragma unroll
    for (int mf = 0; mf < 4; mf++) {
        int mbase = m0 + wm * 64 + mf * 16 + q * 4;
        #pragma unroll
        for (int nf = 0; nf < 4; nf++) {
            int n = n0 + wn * 64 + nf * 16 + lm;
            if (n < N) {
                #pragma unroll
                for (int r = 0; r < 4; r++) {
                    float v = acc[mf][nf][r];
                    size_t ci = (size_t)(mbase + r) * ldc + n;
                    if (flags & 4) {
                        v = silu_f(v + bias[n]);
                        ((__bf16*)C)[ci] = (__bf16)v;
                    } else if (flags & 8) {
                        C[ci + (size_t)blockIdx.z * pstr] = v;
                    } else if (flags & 2) {
                        atomicAdd(C + ci, v);
                    } else {
                        C[ci] = v;
                    }
                }
            }
        }
    }
}

// ---------------- final GEMM: hcat gather fused; split-K 2 (z=0 fwd half, z=1 bwd half) ----------------
__global__ __launch_bounds__(256) void final_gemm(
    const float* __restrict__ h_all, const __bf16* __restrict__ poT,
    float* __restrict__ out) {
    __shared__ __bf16 Asm_[128][40];
    __shared__ char Bsm[8192];
    int tid = threadIdx.x;
    int m0 = blockIdx.y * 128;
    int z = blockIdx.z;
    int w = tid >> 6, l = tid & 63;
    int wm = w >> 1, wn_ = w & 1, lm = l & 15, q = l >> 4;
    f32x4 acc[4][4];
    #pragma unroll
    for (int i = 0; i < 4; i++)
        #pragma unroll
        for (int j = 0; j < 4; j++) acc[i][j] = (f32x4)0.f;

    int r = tid >> 1, half = tid & 1;
    int m = m0 + r;
    int b = m >> 7, jj = m & 127;
    size_t arow = (z == 0) ? ((size_t)(b * NTOK + NVIS + jj) * 256)
                           : ((size_t)MFWD * 256 + (size_t)(b * TBWD + (TBWD - 1 - jj)) * 256);
    for (int k0 = 0; k0 < 256; k0 += 32) {
        {
            const float4* sp = (const float4*)(h_all + arow + k0 + half * 16);
            float4 v0 = sp[0], v1 = sp[1], v2 = sp[2], v3 = sp[3];
            union { uint4 u; __bf16 hh[8]; } d0, d1;
            d0.hh[0] = (__bf16)v0.x; d0.hh[1] = (__bf16)v0.y; d0.hh[2] = (__bf16)v0.z; d0.hh[3] = (__bf16)v0.w;
            d0.hh[4] = (__bf16)v1.x; d0.hh[5] = (__bf16)v1.y; d0.hh[6] = (__bf16)v1.z; d0.hh[7] = (__bf16)v1.w;
            d1.hh[0] = (__bf16)v2.x; d1.hh[1] = (__bf16)v2.y; d1.hh[2] = (__bf16)v2.z; d1.hh[3] = (__bf16)v2.w;
            d1.hh[4] = (__bf16)v3.x; d1.hh[5] = (__bf16)v3.y; d1.hh[6] = (__bf16)v3.z; d1.hh[7] = (__bf16)v3.w;
            *(uint4*)&Asm_[r][half * 16] = d0.u;
            *(uint4*)&Asm_[r][half * 16 + 8] = d1.u;
        }
        #pragma unroll
        for (int i = 0; i < 2; i++) {
            int s = i * 256 + tid;
            ASYNC16(poT + (size_t)(s >> 2) * 512 + z * 256 + k0 + (s & 3) * 8, Bsm + s * 16);
        }
        __syncthreads();
        bf16x8 af[4], bfr[4];
        #pragma unroll
        for (int mf = 0; mf < 4; mf++)
            af[mf] = *(const bf16x8*)&Asm_[wm * 64 + mf * 16 + lm][q * 8];
        #pragma unroll
        for (int nf = 0; nf < 4; nf++)
            bfr[nf] = *(const bf16x8*)(Bsm + (wn_ * 64 + nf * 16 + lm) * 64 + q * 16);
        #pragma unroll
        for (int mf = 0; mf < 4; mf++)
            #pragma unroll
            for (int nf = 0; nf < 4; nf++)
                acc[mf][nf] = __builtin_amdgcn_mfma_f32_16x16x32_bf16(af[mf], bfr[nf], acc[mf][nf], 0, 0, 0);
        __syncthreads();
    }
    #pragma unroll
    for (int mf = 0; mf < 4; mf++) {
        int mbase = m0 + wm * 64 + mf * 16 + q * 4;
        #pragma unroll
        for (int nf = 0; nf < 4; nf++) {
            int n = wn_ * 64 + nf * 16 + lm;
            #pragma unroll
            for (int rr = 0; rr < 4; rr++)
                atomicAdd(out + (size_t)(mbase + rr) * 128 + n, acc[mf][nf][rr]);
        }
    }
}

// ---------------- fused inproj GEMM (fwd+bwd batched) with rmsnorm prologue ----------------
__global__ __launch_bounds__(256) void gemm_inproj_norm(
    const float* __restrict__ h, const float* __restrict__ wnf, const float* __restrict__ wnb,
    const __bf16* __restrict__ ipTf, const __bf16* __restrict__ ipTb,
    float* __restrict__ C) {
    __shared__ __bf16 Asm[128][264];
    __shared__ char Bsm[8192];
    int tid = threadIdx.x;
    int m0 = blockIdx.y * 128, n0 = blockIdx.x * 128;
    int dir = (m0 >= MFWD);
    const float* wnorm = dir ? wnb : wnf;
    const __bf16* Bt = dir ? ipTb : ipTf;
    {
        int row = tid >> 1, half = tid & 1;
        const float4* xr = (const float4*)(h + (size_t)(m0 + row) * 256 + half * 128);
        const float4* wr = (const float4*)(wnorm + half * 128);
        float ss = 0.f;
        #pragma unroll
        for (int c = 0; c < 32; c++) {
            float4 v = xr[c], wv = wr[c];
            ss += v.x * v.x + v.y * v.y + v.z * v.z + v.w * v.w;
            __bf16 t4b[4] = {(__bf16)(v.x * wv.x), (__bf16)(v.y * wv.y),
                             (__bf16)(v.z * wv.z), (__bf16)(v.w * wv.w)};
            *(uint2*)&Asm[row][half * 128 + c * 4] = *(uint2*)t4b;
        }
        ss += __shfl_xor(ss, 1);
        float rs = rsqrtf(ss * (1.f / 256.f) + 1e-5f);
        #pragma unroll
        for (int c = 0; c < 16; c++) {
            union { uint4 u; __bf16 hh[8]; } a;
            a.u = *(uint4*)&Asm[row][half * 128 + c * 8];
            #pragma unroll
            for (int j = 0; j < 8; j++) a.hh[j] = (__bf16)((float)a.hh[j] * rs);
            *(uint4*)&Asm[row][half * 128 + c * 8] = a.u;
        }
    }
    __syncthreads();
    int w = tid >> 6, l = tid & 63;
    int wm = w >> 1, wn_ = w & 1, lm = l & 15, q = l >> 4;
    f32x4 acc[4][4];
    #pragma unroll
    for (int i = 0; i < 4; i++)
        #pragma unroll
        for (int j = 0; j < 4; j++) acc[i][j] = (f32x4)0.f;
    for (int k0 = 0; k0 < 256; k0 += 32) {
        #pragma unroll
        for (int i = 0; i < 2; i++) {
            int s = i * 256 + tid;
            ASYNC16(Bt + (size_t)(n0 + (s >> 2)) * 256 + k0 + (s & 3) * 8, Bsm + s * 16);
        }
        __syncthreads();
        bf16x8 af[4], bfr[4];
        #pragma unroll
        for (int mf = 0; mf < 4; mf++)
            af[mf] = *(const bf16x8*)&Asm[wm * 64 + mf * 16 + lm][k0 + q * 8];
        #pragma unroll
        for (int nf = 0; nf < 4; nf++)
            bfr[nf] = *(const bf16x8*)(Bsm + (wn_ * 64 + nf * 16 + lm) * 64 + q * 16);
        #pragma unroll
        for (int mf = 0; mf < 4; mf++)
            #pragma unroll
            for (int nf = 0; nf < 4; nf++)
                acc[mf][nf] = __builtin_amdgcn_mfma_f32_16x16x32_bf16(af[mf], bfr[nf], acc[mf][nf], 0, 0, 0);
        __syncthreads();
    }
    #pragma unroll
    for (int mf = 0; mf < 4; mf++) {
        int mbase = m0 + wm * 64 + mf * 16 + q * 4;
        #pragma unroll
        for (int nf = 0; nf < 4; nf++) {
            int n = n0 + wn_ * 64 + nf * 16 + lm;
            if (n < DPROJ) {
                #pragma unroll
                for (int r = 0; r < 4; r++)
                    C[(size_t)(mbase + r) * DPROJ + n] = acc[mf][nf][r];
            }
        }
    }
}

// ---------------- fused outproj GEMM (batched, layer-aware rows) with gated-rmsnorm prologue ----------------
__global__ __launch_bounds__(256) void gemm_outproj_gated(
    const __bf16* __restrict__ ysD, const float* __restrict__ zx,
    const float* __restrict__ gwf, const float* __restrict__ gwb,
    const __bf16* __restrict__ opTf, const __bf16* __restrict__ opTb,
    float* __restrict__ C, int layer) {
    __shared__ __bf16 Asm[64][520];
    __shared__ char Bsm[8192];
    int tid = threadIdx.x;
    int yb = blockIdx.y;
    int m0;
    if (layer == 0) m0 = yb * 64;
    else m0 = (yb < 16) ? ((yb >> 1) * 512 + 384 + (yb & 1) * 64) : (MFWD + (yb - 16) * 64);
    int n0 = blockIdx.x * 128;
    int dir = (m0 >= MFWD);
    const float* gw = dir ? gwb : gwf;
    const __bf16* Bt = dir ? opTb : opTf;
    {
        int row = tid >> 2, part = tid & 3;
        size_t gm = m0 + row;
        const uint4* yr = (const uint4*)(ysD + gm * 512 + part * 128);
        const float4* zr = (const float4*)(zx + gm * DPROJ + part * 128);
        const float4* gr = (const float4*)(gw + part * 128);
        float ss = 0.f;
        #pragma unroll
        for (int c = 0; c < 16; c++) {
            union { uint4 u; __bf16 hh[8]; } yv; yv.u = yr[c];
            float4 z0 = zr[c * 2], z1 = zr[c * 2 + 1];
            float4 g0 = gr[c * 2], g1 = gr[c * 2 + 1];
            float gg[8];
            gg[0] = (float)yv.hh[0] * silu_f(z0.x);
            gg[1] = (float)yv.hh[1] * silu_f(z0.y);
            gg[2] = (float)yv.hh[2] * silu_f(z0.z);
            gg[3] = (float)yv.hh[3] * silu_f(z0.w);
            gg[4] = (float)yv.hh[4] * silu_f(z1.x);
            gg[5] = (float)yv.hh[5] * silu_f(z1.y);
            gg[6] = (float)yv.hh[6] * silu_f(z1.z);
            gg[7] = (float)yv.hh[7] * silu_f(z1.w);
            #pragma unroll
            for (int j = 0; j < 8; j++) ss += gg[j] * gg[j];
            union { uint4 u; __bf16 hh[8]; } d;
            d.hh[0] = (__bf16)(gg[0] * g0.x); d.hh[1] = (__bf16)(gg[1] * g0.y);
            d.hh[2] = (__bf16)(gg[2] * g0.z); d.hh[3] = (__bf16)(gg[3] * g0.w);
            d.hh[4] = (__bf16)(gg[4] * g1.x); d.hh[5] = (__bf16)(gg[5] * g1.y);
            d.hh[6] = (__bf16)(gg[6] * g1.z); d.hh[7] = (__bf16)(gg[7] * g1.w);
            *(uint4*)&Asm[row][part * 128 + c * 8] = d.u;
        }
        ss += __shfl_xor(ss, 1);
        ss += __shfl_xor(ss, 2);
        float rs = rsqrtf(ss * (1.f / 512.f) + 1e-5f);
        #pragma unroll
        for (int c = 0; c < 16; c++) {
            union { uint4 u; __bf16 hh[8]; } a;
            a.u = *(uint4*)&Asm[row][part * 128 + c * 8];
            #pragma unroll
            for (int j = 0; j < 8; j++) a.hh[j] = (__bf16)((float)a.hh[j] * rs);
            *(uint4*)&Asm[row][part * 128 + c * 8] = a.u;
        }
    }
    __syncthreads();
    int w = tid >> 6, l = tid & 63;
    int wm = w >> 1, wn_ = w & 1, lm = l & 15, q = l >> 4;
    f32x4 acc[2][4];
    #pragma unroll
    for (int i = 0; i < 2; i++)
        #pragma unroll
        for (int j = 0; j < 4; j++) acc[i][j] = (f32x4)0.f;
    for (int k0 = 0; k0 < 512; k0 += 32) {
        #pragma unroll
        for (int i = 0; i < 2; i++) {
            int s = i * 256 + tid;
            ASYNC16(Bt + (size_t)(n0 + (s >> 2)) * 512 + k0 + (s & 3) * 8, Bsm + s * 16);
        }
        __syncthreads();
        bf16x8 af[2], bfr[4];
        #pragma unroll
        for (int mf = 0; mf < 2; mf++)
            af[mf] = *(const bf16x8*)&Asm[wm * 32 + mf * 16 + lm][k0 + q * 8];
        #pragma unroll
        for (int nf = 0; nf < 4; nf++)
            bfr[nf] = *(const bf16x8*)(Bsm + (wn_ * 64 + nf * 16 + lm) * 64 + q * 16);
        #pragma unroll
        for (int mf = 0; mf < 2; mf++)
            #pragma unroll
            for (int nf = 0; nf < 4; nf++)
                acc[mf][nf] = __builtin_amdgcn_mfma_f32_16x16x32_bf16(af[mf], bfr[nf], acc[mf][nf], 0, 0, 0);
        __syncthreads();
    }
    #pragma unroll
    for (int mf = 0; mf < 2; mf++) {
        int mbase = m0 + wm * 32 + mf * 16 + q * 4;
        #pragma unroll
        for (int nf = 0; nf < 4; nf++) {
            int n = n0 + wn_ * 64 + nf * 16 + lm;
            #pragma unroll
            for (int r = 0; r < 4; r++) {
                size_t ci = (size_t)(mbase + r) * DMODEL + n;
                C[ci] += acc[mf][nf][r];      // disjoint (m,n) per block
            }
        }
    }
}

// ---------------- segmented prep kernel (all coalesced) ----------------
__global__ void prep_all(const float* __restrict__ pre_conv_w, const float* __restrict__ patch_w,
                         const float* __restrict__ ip0, const float* __restrict__ ip1,
                         const float* __restrict__ op0, const float* __restrict__ op1,
                         const float* __restrict__ pow_, const float* __restrict__ pob,
                         const float* __restrict__ y_aux, const float* __restrict__ aux_w,
                         const float* __restrict__ aux_b, const float* __restrict__ xp,
                         __bf16* __restrict__ WpreT, __bf16* __restrict__ WtT,
                         __bf16* __restrict__ inprojT, __bf16* __restrict__ outprojT,
                         __bf16* __restrict__ poT, float* __restrict__ auxb,
                         float* __restrict__ dout, __bf16* __restrict__ Aim) {
    __shared__ float tile[32][33];
    int bx = blockIdx.x, tid = threadIdx.x;
    int tx = tid & 31, ty = tid >> 5;
    if (bx < 256) {
        int o = bx, c = tid;
        float f[16];
        const float4* s = (const float4*)(patch_w + (size_t)o * 4096 + c * 16);
        #pragma unroll
        for (int j = 0; j < 4; j++) *(float4*)&f[j * 4] = s[j];
        #pragma unroll
        for (int k = 0; k < 16; k++)
            WtT[(size_t)o * 4096 + k * 256 + c] = (__bf16)f[k];
        return;
    }
    bx -= 256;
    if (bx < 1152) {
        int seg = bx / 288, rem = bx % 288;
        int n0 = (rem / 8) * 32, k0 = (rem % 8) * 32;
        const float* src = (seg < 2 ? ip0 : ip1) + (size_t)(seg & 1) * 256 * DPROJ;
        #pragma unroll
        for (int j = 0; j < 4; j++) {
            int r = ty + j * 8;
            int n = n0 + tx;
            tile[r][tx] = (n < DPROJ) ? src[(size_t)(k0 + r) * DPROJ + n] : 0.f;
        }
        __syncthreads();
        __bf16* dst = inprojT + (size_t)seg * 1152 * 256;
        #pragma unroll
        for (int j = 0; j < 4; j++) {
            int r = ty + j * 8;
            dst[(size_t)(n0 + r) * 256 + k0 + tx] = (__bf16)tile[tx][r];
        }
        return;
    }
    bx -= 1152;
    if (bx < 512) {
        int s = bx / 128, rem = bx % 128;
        int n0 = (rem / 16) * 32, k0 = (rem % 16) * 32;
        const float* src = (s < 2 ? op0 : op1) + (size_t)(s & 1) * DINNER * DMODEL;
        #pragma unroll
        for (int j = 0; j < 4; j++) {
            int r = ty + j * 8;
            tile[r][tx] = src[(size_t)(k0 + r) * 256 + n0 + tx];
        }
        __syncthreads();
        __bf16* dst = outprojT + (size_t)s * 256 * 512;
        #pragma unroll
        for (int j = 0; j < 4; j++) {
            int r = ty + j * 8;
            dst[(size_t)(n0 + r) * 512 + k0 + tx] = (__bf16)tile[tx][r];
        }
        return;
    }
    bx -= 512;
    if (bx < 64) {
        int n0 = (bx / 16) * 32, k0 = (bx % 16) * 32;
        #pragma unroll
        for (int j = 0; j < 4; j++) {
            int r = ty + j * 8;
            tile[r][tx] = pow_[(size_t)(k0 + r) * 128 + n0 + tx];
        }
        __syncthreads();
        #pragma unroll
        for (int j = 0; j < 4; j++) {
            int r = ty + j * 8;
            poT[(size_t)(n0 + r) * 512 + k0 + tx] = (__bf16)tile[tx][r];
        }
        return;
    }
    bx -= 64;
    if (bx < 64) {
        int idx = bx * 256 + tid;
        int o = idx >> 6, kk = idx & 63;
        WpreT[idx] = (kk < 40) ? (__bf16)pre_conv_w[o * 40 + kk] : (__bf16)0.f;
        return;
    }
    bx -= 64;
    if (bx < 512) {
        int idx = bx * 256 + tid;
        dout[idx] = pob[idx & 127];
        return;
    }
    bx -= 512;
    if (bx < 192) {
        int m = bx * 256 + tid;
        int t = m % TPREF, b = m / TPREF;
        __bf16 d[64];
        #pragma unroll
        for (int k = 0; k < 5; k++) {
            int tt = t - 2 + k;
            bool ok = (tt >= 0) && (tt < TPREF);
            const float* s = xp + ((size_t)b * TPREF + tt) * 8;
            #pragma unroll
            for (int i = 0; i < 8; i++)
                d[i * 5 + k] = ok ? (__bf16)s[i] : (__bf16)0.f;
        }
        #pragma unroll
        for (int j = 40; j < 64; j++) d[j] = (__bf16)0.f;
        uint4* o = (uint4*)(Aim + (size_t)m * 64);
        #pragma unroll
        for (int k = 0; k < 8; k++) o[k] = ((const uint4*)d)[k];
        return;
    }
    bx -= 192;
    {
        int b = bx, o = tid;
        float acc = aux_b[o];
        #pragma unroll
        for (int i = 0; i < 16; i++) acc += y_aux[b * 16 + i] * aux_w[i * 256 + o];
        auxb[b * 256 + o] = silu_f(acc);
    }
}

// assemble: sum 8 patch partials + bias, build h_all
__global__ void assemble_kernel(const float* __restrict__ Cp8, const float* __restrict__ pb,
                                const float* __restrict__ mtok, const float* __restrict__ aux,
                                float* __restrict__ h_all) {
    int idx = blockIdx.x * 256 + threadIdx.x;
    if (idx >= BSZ * NTOK * DMODEL) return;
    int o = idx & 255, tok = (idx >> 8) & 511, b = idx >> 17;
    float v;
    if (tok < NVIS) {
        size_t ci = (size_t)(b * NVIS + tok) * 256 + o;
        v = pb[o];
        #pragma unroll
        for (int z = 0; z < 8; z++) v += Cp8[ci + (size_t)z * 3072 * 256];
    } else {
        v = mtok[o];
    }
    v += aux[b * 256 + o];
    h_all[idx] = v;
    if (tok >= NVIS)
        h_all[(size_t)MFWD * 256 + (size_t)(b * TBWD + (NTOK - 1 - tok)) * 256 + o] = v;
}

// causal depthwise conv (k=4) + bias + silu; fwd+bwd batched. grid (9, 80)
__global__ __launch_bounds__(256) void dwconv2_kernel(
    const float* __restrict__ zx, const float* __restrict__ cwf, const float* __restrict__ cbf,
    const float* __restrict__ cwb, const float* __restrict__ cbb,
    __bf16* __restrict__ XtF, __bf16* __restrict__ XtB,
    __bf16* __restrict__ BCF, __bf16* __restrict__ BCB) {
    int cg = blockIdx.x;
    int id = blockIdx.y;
    int b, t0, T; size_t rowbase;
    const float *cw, *cb; __bf16 *Xt, *BC;
    if (id < 64) { b = id >> 3; t0 = (id & 7) * 64; T = NTOK; rowbase = (size_t)b * NTOK;
                   cw = cwf; cb = cbf; Xt = XtF; BC = BCF; }
    else { int i2 = id - 64; b = i2 >> 1; t0 = (i2 & 1) * 64; T = TBWD;
           rowbase = (size_t)MFWD + (size_t)b * TBWD; cw = cwb; cb = cbb; Xt = XtB; BC = BCB; }
    int c0 = cg * 64;
    __shared__ float xs[67][65];
    int lane = threadIdx.x & 63, grp = threadIdx.x >> 6;
    for (int r = grp; r < 67; r += 4) {
        int t = t0 - 3 + r;
        xs[r][lane] = (t >= 0) ? zx[(rowbase + t) * DPROJ + DINNER + c0 + lane] : 0.f;
    }
    __syncthreads();
    if (cg < 8) {
        int t = lane;
        #pragma unroll
        for (int ci = grp; ci < 64; ci += 4) {
            int c = c0 + ci;
            float acc = cb[c];
            #pragma unroll
            for (int k = 0; k < 4; k++) acc += cw[c * 4 + k] * xs[t + k][ci];
            Xt[((size_t)((b * 8 + cg) * 64 + ci)) * T + t0 + t] = (__bf16)silu_f(acc);
        }
    } else {
        int c = lane;
        #pragma unroll
        for (int ti = grp; ti < 64; ti += 4) {
            float acc = cb[c0 + c];
            #pragma unroll
            for (int k = 0; k < 4; k++) acc += cw[(c0 + c) * 4 + k] * xs[ti + k][c];
            BC[((size_t)(b * T + t0 + ti)) * 64 + c] = (__bf16)silu_f(acc);
        }
    }
}

// ---------------- chunked SSD scan phase A (fwd+bwd batched, layer-aware). grid (80, 8) ----------------
__global__ __launch_bounds__(64) void scan_local(
    const __bf16* __restrict__ XtF, const __bf16* __restrict__ XtB,
    const __bf16* __restrict__ BCF, const __bf16* __restrict__ BCB,
    const float* __restrict__ zx,
    const float* __restrict__ dtbf, const float* __restrict__ dtbb,
    const float* __restrict__ Alogf, const float* __restrict__ Alogb,
    const float* __restrict__ Dpf, const float* __restrict__ Dpb,
    __bf16* __restrict__ ysD,
    __bf16* __restrict__ ChatF, __bf16* __restrict__ ChatB,
    float* __restrict__ dSF, float* __restrict__ dSB,
    float* __restrict__ DcsF, float* __restrict__ DcsB, int layer) {
    int id = blockIdx.x, hd = blockIdx.y;
    int b, c, T, NC; size_t rowbase;
    const __bf16 *Xt, *BC; __bf16* Chat; float *dS, *Dcs;
    const float *dtb, *Alog, *Dp;
    if (id < 64) { b = id >> 3; c = id & 7; T = NTOK; NC = 8; rowbase = (size_t)b * NTOK;
                   Xt = XtF; BC = BCF; Chat = ChatF; dS = dSF; Dcs = DcsF;
                   dtb = dtbf; Alog = Alogf; Dp = Dpf; }
    else { int i2 = id - 64; b = i2 >> 1; c = i2 & 1; T = TBWD; NC = 2;
           rowbase = (size_t)MFWD + (size_t)b * TBWD;
           Xt = XtB; BC = BCB; Chat = ChatB; dS = dSB; Dcs = DcsB;
           dtb = dtbb; Alog = Alogb; Dp = Dpb; }
    bool skipY = (layer == 1) && (id < 64) && (c < 6);   // layer-2 fwd t<384: Y unused
    int bh = b * 8 + hd;
    int t0 = c * 64;
    int lane = threadIdx.x;
    int lm = lane & 15, q = lane >> 4;
    float A = -expf(Alog[hd]);
    float Dh = Dp[hd];

    // overlaid LDS: Pl aliases BCl (BCl dead once cfr/bfr frags are in regs; 1 wave/block)
    __shared__ char smem[23552];
    __bf16 (*Xl)[72]  = (__bf16(*)[72])(smem);
    __bf16 (*BCl)[72] = (__bf16(*)[72])(smem + 9216);
    __bf16 (*Pl)[72]  = (__bf16(*)[72])(smem + 9216);
    __bf16 (*Wbl)[72] = (__bf16(*)[72])(smem + 18432);
    float* lcs = (float*)(smem + 23040);
    float* dts = (float*)(smem + 23296);

    const uint4* xg = (const uint4*)(Xt + (size_t)(bh * 64 + lane) * T + t0);
    const uint4* bg = (const uint4*)(BC + ((size_t)(b * T + t0 + lane)) * 64);
    uint4 xv[8], bv[8];
    #pragma unroll
    for (int k = 0; k < 8; k++) { xv[k] = xg[k]; bv[k] = bg[k]; }
    float xdt = zx[(rowbase + t0 + lane) * DPROJ + 1088 + hd] + dtb[hd];
    float dtv = (xdt > 20.f) ? xdt : log1pf(expf(xdt));
    #pragma unroll
    for (int k = 0; k < 8; k++) {
        *(uint4*)&Xl[lane][k * 8] = xv[k];
        if (!skipY) *(uint4*)&BCl[lane][k * 8] = bv[k];
    }
    float lc = A * dtv;
    #pragma unroll
    for (int off = 1; off < 64; off <<= 1) {
        float o = __shfl_up(lc, off);
        if (lane >= off) lc += o;
    }
    lcs[lane] = lc; dts[lane] = dtv;
    float lc63 = __shfl(lc, 63);
    float wj = expf(lc63 - lc) * dtv;
    float eli = expf(lc);
    float Dc = expf(lc63);
    if (lane == 0) Dcs[bh * NC + c] = Dc;
    if (!skipY) {
        __bf16* co = Chat + ((size_t)(bh * NC + c) * 64 + lane) * 32;
        #pragma unroll
        for (int k = 0; k < 4; k++) {
            union { uint4 u; __bf16 h[8]; } s; s.u = bv[4 + k];
            union { uint4 u; __bf16 h[8]; } d;
            #pragma unroll
            for (int j = 0; j < 8; j++) d.h[j] = (__bf16)(eli * (float)s.h[j]);
            *(uint4*)(co + k * 8) = d.u;
        }
    }
    #pragma unroll
    for (int k = 0; k < 4; k++) {
        union { uint4 u; __bf16 h[8]; } s; s.u = bv[k];
        #pragma unroll
        for (int j = 0; j < 8; j++) Wbl[k * 8 + j][lane] = (__bf16)(wj * (float)s.h[j]);
    }
    __syncthreads();

    bf16x8 xf0[4], xf1[4];
    if (!skipY) {
        bf16x8 cfr[4], bfr[4];
        #pragma unroll
        for (int t4 = 0; t4 < 4; t4++) {
            cfr[t4] = *(const bf16x8*)&BCl[t4 * 16 + lm][32 + q * 8];
            bfr[t4] = *(const bf16x8*)&BCl[t4 * 16 + lm][q * 8];
        }
        #pragma unroll
        for (int ti = 0; ti < 4; ti++) {
            float lci[4];
            #pragma unroll
            for (int r = 0; r < 4; r++) lci[r] = lcs[ti * 16 + q * 4 + r];
            #pragma unroll
            for (int tj = 0; tj < 4; tj++) {
                if (tj > ti) {
                    #pragma unroll
                    for (int r = 0; r < 4; r++) Pl[ti * 16 + q * 4 + r][tj * 16 + lm] = (__bf16)0.f;
                    continue;
                }
                f32x4 g = __builtin_amdgcn_mfma_f32_16x16x32_bf16(cfr[ti], bfr[tj], (f32x4)0.f, 0, 0, 0);
                int j = tj * 16 + lm;
                float lcj = lcs[j], dtj = dts[j];
                #pragma unroll
                for (int r = 0; r < 4; r++) {
                    int i = ti * 16 + q * 4 + r;
                    float v = (j <= i) ? g[r] * expf(lci[r] - lcj) * dtj : 0.f;
                    if (j == i) v += Dh;
                    Pl[i][j] = (__bf16)v;
                }
            }
        }
        __syncthreads();

        bf16x8 pf0[4], pf1[4];
        #pragma unroll
        for (int t4 = 0; t4 < 4; t4++) {
            pf0[t4] = *(const bf16x8*)&Pl[t4 * 16 + lm][q * 8];
            pf1[t4] = *(const bf16x8*)&Pl[t4 * 16 + lm][32 + q * 8];
            xf0[t4] = *(const bf16x8*)&Xl[t4 * 16 + lm][q * 8];
            xf1[t4] = *(const bf16x8*)&Xl[t4 * 16 + lm][32 + q * 8];
        }
        #pragma unroll
        for (int ti = 0; ti < 4; ti++) {
            #pragma unroll
            for (int tp = 0; tp < 4; tp++) {
                f32x4 y = __builtin_amdgcn_mfma_f32_16x16x32_bf16(pf0[ti], xf0[tp], (f32x4)0.f, 0, 0, 0);
                y = __builtin_amdgcn_mfma_f32_16x16x32_bf16(pf1[ti], xf1[tp], y, 0, 0, 0);
                #pragma unroll
                for (int r = 0; r < 4; r++) {
                    int i = ti * 16 + q * 4 + r;
                    ysD[(rowbase + t0 + i) * DINNER + hd * 64 + tp * 16 + lm] = (__bf16)y[r];
                }
            }
        }
    } else {
        #pragma unroll
        for (int t4 = 0; t4 < 4; t4++) {
            xf0[t4] = *(const bf16x8*)&Xl[t4 * 16 + lm][q * 8];
            xf1[t4] = *(const bf16x8*)&Xl[t4 * 16 + lm][32 + q * 8];
        }
    }
    bf16x8 wf0[2], wf1[2];
    #pragma unroll
    for (int tn = 0; tn < 2; tn++) {
        wf0[tn] = *(const bf16x8*)&Wbl[tn * 16 + lm][q * 8];
        wf1[tn] = *(const bf16x8*)&Wbl[tn * 16 + lm][32 + q * 8];
    }
    float* dso = dS + (size_t)(bh * NC + c) * 2048;
    #pragma unroll
    for (int tp = 0; tp < 4; tp++) {
        #pragma unroll
        for (int tn = 0; tn < 2; tn++) {
            f32x4 s = __builtin_amdgcn_mfma_f32_16x16x32_bf16(xf0[tp], wf0[tn], (f32x4)0.f, 0, 0, 0);
            s = __builtin_amdgcn_mfma_f32_16x16x32_bf16(xf1[tp], wf1[tn], s, 0, 0, 0);
            #pragma unroll
            for (int r = 0; r < 4; r++) {
                int pp = tp * 16 + q * 4 + r, nn = tn * 16 + lm;
                dso[pp * 32 + nn] = s[r];
            }
        }
    }
}

// ---------------- scan tail (batched, layer-aware): recurrence + cross-chunk Y add ----------------
__global__ __launch_bounds__(256) void scan_tail(
    const float* __restrict__ dSF, const float* __restrict__ dSB,
    const float* __restrict__ DcsF, const float* __restrict__ DcsB,
    const __bf16* __restrict__ ChatF, const __bf16* __restrict__ ChatB,
    __bf16* __restrict__ ysD, int layer) {
    int blk = blockIdx.x;
    int dir = blk >= 64;
    int bh = blk & 63;
    int NC = dir ? 2 : 8;
    int T = dir ? TBWD : NTOK;
    int b = bh >> 3, hd = bh & 7;
    size_t rowbase = dir ? ((size_t)MFWD + (size_t)b * TBWD) : ((size_t)b * NTOK);
    const float* dS = dir ? dSB : dSF;
    const float* Dcs = dir ? DcsB : DcsF;
    const __bf16* Chat = dir ? ChatB : ChatF;
    int cmin = (layer == 1 && !dir) ? 6 : 1;   // layer-2 fwd: Y only needed for chunks 6,7
    int tid = threadIdx.x;
    __shared__ __bf16 Spl[8][64][40];
    {
        int p = tid >> 2, n0 = (tid & 3) * 8;
        float S[8];
        #pragma unroll
        for (int j = 0; j < 8; j++) S[j] = 0.f;
        for (int c = 0; c < NC; c++) {
            union { uint4 u; __bf16 hh[8]; } o;
            #pragma unroll
            for (int j = 0; j < 8; j++) o.hh[j] = (__bf16)S[j];
            *(uint4*)&Spl[c][p][n0] = o.u;
            float Dc = Dcs[bh * NC + c];
            const float4* dp = (const float4*)(dS + ((size_t)(bh * NC + c)) * 2048 + tid * 8);
            float4 d0 = dp[0], d1 = dp[1];
            S[0] = Dc * S[0] + d0.x; S[1] = Dc * S[1] + d0.y;
            S[2] = Dc * S[2] + d0.z; S[3] = Dc * S[3] + d0.w;
            S[4] = Dc * S[4] + d1.x; S[5] = Dc * S[5] + d1.y;
            S[6] = Dc * S[6] + d1.z; S[7] = Dc * S[7] + d1.w;
        }
    }
    __syncthreads();
    int w = tid >> 6, l = tid & 63, lm = l & 15, q = l >> 4;
    for (int c = cmin + w; c < NC; c += 4) {
        int t0 = c * 64;
        const __bf16* Cb = Chat + (size_t)(bh * NC + c) * 2048;
        bf16x8 cf[4], sf[4];
        #pragma unroll
        for (int t4 = 0; t4 < 4; t4++) {
            cf[t4] = *(const bf16x8*)(Cb + (t4 * 16 + lm) * 32 + q * 8);
            sf[t4] = *(const bf16x8*)&Spl[c][t4 * 16 + lm][q * 8];
        }
        #pragma unroll
        for (int ti = 0; ti < 4; ti++) {
            #pragma unroll
            for (int tp = 0; tp < 4; tp++) {
                f32x4 y = __builtin_amdgcn_mfma_f32_16x16x32_bf16(cf[ti], sf[tp], (f32x4)0.f, 0, 0, 0);
                #pragma unroll
                for (int r = 0; r < 4; r++) {
                    int i = ti * 16 + q * 4 + r;
                    size_t idx = (rowbase + t0 + i) * DINNER + hd * 64 + tp * 16 + lm;
                    ysD[idx] = (__bf16)((float)ysD[idx] + y[r]);
                }
            }
        }
    }
}

// ---------------- launch ----------------
extern "C" void kernel_launch(void* const* d_in, const int* in_sizes, int n_in,
                              void* d_out, int out_size, void* d_ws, size_t ws_size,
                              hipStream_t stream) {
    const float* x_prefix    = (const float*)d_in[0];
    const float* y_aux       = (const float*)d_in[1];
    const float* pre_conv_w  = (const float*)d_in[2];
    const float* pre_conv_b  = (const float*)d_in[3];
    const float* patch_w     = (const float*)d_in[4];
    const float* patch_b     = (const float*)d_in[5];
    const float* mask_token  = (const float*)d_in[6];
    const float* aux_w       = (const float*)d_in[7];
    const float* aux_b       = (const float*)d_in[8];
    const float* patch_out_w = (const float*)d_in[9];
    const float* patch_out_b = (const float*)d_in[10];
    const float* w_norm[2]   = {(const float*)d_in[11], (const float*)d_in[20]};
    const float* w_inproj[2] = {(const float*)d_in[12], (const float*)d_in[21]};
    const float* w_convw[2]  = {(const float*)d_in[13], (const float*)d_in[22]};
    const float* w_convb[2]  = {(const float*)d_in[14], (const float*)d_in[23]};
    const float* w_dtb[2]    = {(const float*)d_in[15], (const float*)d_in[24]};
    const float* w_alog[2]   = {(const float*)d_in[16], (const float*)d_in[25]};
    const float* w_D[2]      = {(const float*)d_in[17], (const float*)d_in[26]};
    const float* w_gnorm[2]  = {(const float*)d_in[18], (const float*)d_in[27]};
    const float* w_outproj[2]= {(const float*)d_in[19], (const float*)d_in[28]};

    char* p = (char*)d_ws;
    auto alloc = [&](size_t bytes) { char* r = p; p += (bytes + 255) & ~255ULL; return r; };
    __bf16* A_patch  = (__bf16*)alloc((size_t)3072 * 4096 * 2);
    __bf16* Aim      = (__bf16*)alloc((size_t)BSZ * TPREF * 64 * 2);
    __bf16* WpreT    = (__bf16*)alloc((size_t)256 * 64 * 2);
    __bf16* WtT      = (__bf16*)alloc((size_t)256 * 4096 * 2);
    __bf16* inprojT  = (__bf16*)alloc((size_t)4 * 1152 * 256 * 2);
    __bf16* outprojT = (__bf16*)alloc((size_t)4 * 256 * 512 * 2);
    __bf16* poT      = (__bf16*)alloc((size_t)128 * 512 * 2);
    float*  auxb     = (float*)alloc(8 * 256 * 4);
    float*  Cp8      = (float*)alloc((size_t)8 * 3072 * 256 * 4);
    float*  h_all    = (float*)alloc((size_t)MALL * 256 * 4);
    float*  zx       = (float*)alloc((size_t)MALL * DPROJ * 4);
    __bf16* XtF      = (__bf16*)alloc((size_t)64 * 64 * NTOK * 2);
    __bf16* XtB      = (__bf16*)alloc((size_t)64 * 64 * TBWD * 2);
    __bf16* BCF      = (__bf16*)alloc((size_t)BSZ * NTOK * 64 * 2);
    __bf16* BCB      = (__bf16*)alloc((size_t)BSZ * TBWD * 64 * 2);
    __bf16* ysD      = (__bf16*)alloc((size_t)MALL * DINNER * 2);
    __bf16* ChatF    = (__bf16*)alloc((size_t)64 * 8 * 2048 * 2);
    __bf16* ChatB    = (__bf16*)alloc((size_t)64 * 2 * 2048 * 2);
    float*  dSF      = (float*)alloc((size_t)64 * 8 * 2048 * 4);
    float*  dSB      = (float*)alloc((size_t)64 * 2 * 2048 * 4);
    float*  DcsF     = (float*)alloc((size_t)64 * 8 * 4);
    float*  DcsB     = (float*)alloc((size_t)64 * 2 * 4);

    prep_all<<<256 + 1152 + 512 + 64 + 64 + 512 + 192 + 8, 256, 0, stream>>>(
        pre_conv_w, patch_w, w_inproj[0], w_inproj[1], w_outproj[0], w_outproj[1],
        patch_out_w, patch_out_b, y_aux, aux_w, aux_b, x_prefix,
        WpreT, WtT, inprojT, outprojT, poT, auxb, (float*)d_out, Aim);
    gemm_mfma<<<dim3(2, (BSZ * TPREF) / 128, 1), 256, 0, stream>>>(
        Aim, WpreT, (float*)A_patch, pre_conv_b, 256, 64, 256, 4, 0);
    gemm_mfma<<<dim3(2, 24, 8), 256, 0, stream>>>(
        A_patch, WtT, Cp8, nullptr, 256, 4096, 256, 8, (long)3072 * 256);
    assemble_kernel<<<(BSZ * NTOK * DMODEL) / 256, 256, 0, stream>>>(
        Cp8, patch_b, mask_token, auxb, h_all);

    for (int i = 0; i < 2; i++) {
        const __bf16* ipTf = inprojT + (size_t)(0 * 2 + i) * 1152 * 256;
        const __bf16* ipTb = inprojT + (size_t)(1 * 2 + i) * 1152 * 256;
        const __bf16* opTf = outprojT + (size_t)(0 * 2 + i) * 256 * 512;
        const __bf16* opTb = outprojT + (size_t)(1 * 2 + i) * 256 * 512;
        gemm_inproj_norm<<<dim3(9, MALL / 128), 256, 0, stream>>>(
            h_all, w_norm[0] + i * 256, w_norm[1] + i * 256, ipTf, ipTb, zx);
        dwconv2_kernel<<<dim3(9, 80), 256, 0, stream>>>(
            zx, w_convw[0] + i * CONVDIM * 4, w_convb[0] + i * CONVDIM,
            w_convw[1] + i * CONVDIM * 4, w_convb[1] + i * CONVDIM,
            XtF, XtB, BCF, BCB);
        scan_local<<<dim3(80, NHEADS), 64, 0, stream>>>(
            XtF, XtB, BCF, BCB, zx,
            w_dtb[0] + i * 8, w_dtb[1] + i * 8,
            w_alog[0] + i * 8, w_alog[1] + i * 8,
            w_D[0] + i * 8, w_D[1] + i * 8,
            ysD, ChatF, ChatB, dSF, dSB, DcsF, DcsB, i);
        scan_tail<<<128, 256, 0, stream>>>(dSF, dSB, DcsF, DcsB, ChatF, ChatB, ysD, i);
        int oy = (i == 0) ? (MALL / 64) : 32;
        gemm_outproj_gated<<<dim3(2, oy), 256, 0, stream>>>(
            ysD, zx, w_gnorm[0] + i * DINNER, w_gnorm[1] + i * DINNER, opTf, opTb, h_all, i);
    }

    final_gemm<<<dim3(1, 8, 2), 256, 0, stream>>>(h_all, poT, (float*)d_out);
}

// Round 9
// 339.610 us; speedup vs baseline: 1.3159x; 1.3159x over previous
//
#include <hip/hip_runtime.h>
#include <hip/hip_bf16.h>
#include <math.h>

// ---------------- constants ----------------
#define BSZ      8
#define TPREF    6144
#define CIN      8
#define DMODEL   256
#define DINNER   512
#define DSTATE   32
#define NHEADS   8
#define HEADDIM  64
#define CONVDIM  576
#define DPROJ    1096
#define NTOK     512
#define NVIS     384     // unmasked tokens
#define TBWD     128     // bwd truncation (tokens 384..511 reversed)
#define MFWD     (BSZ * NTOK)      // 4096 rows
#define MBWD     (BSZ * TBWD)      // 1024 rows
#define MALL     (MFWD + MBWD)     // 5120 rows

typedef float f32x4 __attribute__((ext_vector_type(4)));
typedef __bf16 bf16x8 __attribute__((ext_vector_type(8)));

__device__ __forceinline__ float silu_f(float x) { return x / (1.f + expf(-x)); }

#define ASYNC16(gp, lp) \
    __builtin_amdgcn_global_load_lds((const __attribute__((address_space(1))) void*)(gp), \
                                     (__attribute__((address_space(3))) void*)(lp), 16, 0, 0)

// ---------------- generic bf16 MFMA GEMM (NT): C[m,n] = sum_k A[m,k]*Bt[n,k] ----------------
// flags: 2 = atomicAdd into fp32 C; 4 = silu(v+bias) + bf16 store; 8 = partial store at z*pstr
__global__ __launch_bounds__(256) void gemm_mfma(
    const __bf16* __restrict__ A, const __bf16* __restrict__ Bt,
    float* __restrict__ C, const float* __restrict__ bias,
    int N, int K, int ldc, int flags, long pstr) {
    __shared__ char sm[16384];
    int tid = threadIdx.x;
    int m0 = blockIdx.y * 128, n0 = blockIdx.x * 128;
    int klen = K / gridDim.z;
    int kbeg = blockIdx.z * klen;
    int w = tid >> 6, l = tid & 63;
    int wm = w >> 1, wn = w & 1;
    int lm = l & 15, q = l >> 4;

    f32x4 acc[4][4];
    #pragma unroll
    for (int i = 0; i < 4; i++)
        #pragma unroll
        for (int j = 0; j < 4; j++) acc[i][j] = (f32x4)0.f;

    for (int k0 = 0; k0 < klen; k0 += 32) {
        int kb = kbeg + k0;
        #pragma unroll
        for (int i = 0; i < 2; i++) {
            int s = i * 256 + tid;
            ASYNC16(A + (size_t)(m0 + (s >> 2)) * K + kb + (s & 3) * 8, sm + s * 16);
        }
        #pragma unroll
        for (int i = 0; i < 2; i++) {
            int s = i * 256 + tid;
            ASYNC16(Bt + (size_t)(n0 + (s >> 2)) * K + kb + (s & 3) * 8, sm + 8192 + s * 16);
        }
        __syncthreads();
        bf16x8 af[4], bfr[4];
        #pragma unroll
        for (int mf = 0; mf < 4; mf++)
            af[mf] = *(const bf16x8*)(sm + (wm * 64 + mf * 16 + lm) * 64 + q * 16);
        #pragma unroll
        for (int nf = 0; nf < 4; nf++)
            bfr[nf] = *(const bf16x8*)(sm + 8192 + (wn * 64 + nf * 16 + lm) * 64 + q * 16);
        #pragma unroll
        for (int mf = 0; mf < 4; mf++)
            #pragma unroll
            for (int nf = 0; nf < 4; nf++)
                acc[mf][nf] = __builtin_amdgcn_mfma_f32_16x16x32_bf16(af[mf], bfr[nf], acc[mf][nf], 0, 0, 0);
        __syncthreads();
    }

    #pragma unroll
    for (int mf = 0; mf < 4; mf++) {
        int mbase = m0 + wm * 64 + mf * 16 + q * 4;
        #pragma unroll
        for (int nf = 0; nf < 4; nf++) {
            int n = n0 + wn * 64 + nf * 16 + lm;
            if (n < N) {
                #pragma unroll
                for (int r = 0; r < 4; r++) {
                    float v = acc[mf][nf][r];
                    size_t ci = (size_t)(mbase + r) * ldc + n;
                    if (flags & 4) {
                        v = silu_f(v + bias[n]);
                        ((__bf16*)C)[ci] = (__bf16)v;
                    } else if (flags & 8) {
                        C[ci + (size_t)blockIdx.z * pstr] = v;
                    } else if (flags & 2) {
                        atomicAdd(C + ci, v);
                    } else {
                        C[ci] = v;
                    }
                }
            }
        }
    }
}

// ---------------- inproj GEMM: 128x128 tile, K=256, dir-selected weights, lean LDS ----------------
__global__ __launch_bounds__(256) void gemm_inproj(
    const __bf16* __restrict__ u, const __bf16* __restrict__ ipTf,
    const __bf16* __restrict__ ipTb, float* __restrict__ C) {
    __shared__ char sm[16384];
    int tid = threadIdx.x;
    int m0 = blockIdx.y * 128, n0 = blockIdx.x * 128;
    const __bf16* Bt = (m0 >= MFWD) ? ipTb : ipTf;
    int w = tid >> 6, l = tid & 63;
    int wm = w >> 1, wn = w & 1, lm = l & 15, q = l >> 4;
    f32x4 acc[4][4];
    #pragma unroll
    for (int i = 0; i < 4; i++)
        #pragma unroll
        for (int j = 0; j < 4; j++) acc[i][j] = (f32x4)0.f;
    for (int k0 = 0; k0 < 256; k0 += 32) {
        #pragma unroll
        for (int i = 0; i < 2; i++) {
            int s = i * 256 + tid;
            ASYNC16(u + (size_t)(m0 + (s >> 2)) * 256 + k0 + (s & 3) * 8, sm + s * 16);
        }
        #pragma unroll
        for (int i = 0; i < 2; i++) {
            int s = i * 256 + tid;
            ASYNC16(Bt + (size_t)(n0 + (s >> 2)) * 256 + k0 + (s & 3) * 8, sm + 8192 + s * 16);
        }
        __syncthreads();
        bf16x8 af[4], bfr[4];
        #pragma unroll
        for (int mf = 0; mf < 4; mf++)
            af[mf] = *(const bf16x8*)(sm + (wm * 64 + mf * 16 + lm) * 64 + q * 16);
        #pragma unroll
        for (int nf = 0; nf < 4; nf++)
            bfr[nf] = *(const bf16x8*)(sm + 8192 + (wn * 64 + nf * 16 + lm) * 64 + q * 16);
        #pragma unroll
        for (int mf = 0; mf < 4; mf++)
            #pragma unroll
            for (int nf = 0; nf < 4; nf++)
                acc[mf][nf] = __builtin_amdgcn_mfma_f32_16x16x32_bf16(af[mf], bfr[nf], acc[mf][nf], 0, 0, 0);
        __syncthreads();
    }
    #pragma unroll
    for (int mf = 0; mf < 4; mf++) {
        int mbase = m0 + wm * 64 + mf * 16 + q * 4;
        #pragma unroll
        for (int nf = 0; nf < 4; nf++) {
            int n = n0 + wn * 64 + nf * 16 + lm;
            if (n < DPROJ) {
                #pragma unroll
                for (int r = 0; r < 4; r++)
                    C[(size_t)(mbase + r) * DPROJ + n] = acc[mf][nf][r];
            }
        }
    }
}

// ---------------- outproj GEMM: 128x128 tile, K=512, dir/layer-aware rows, residual += ----------------
__global__ __launch_bounds__(256) void gemm_outproj(
    const __bf16* __restrict__ y2, const __bf16* __restrict__ opTf,
    const __bf16* __restrict__ opTb, float* __restrict__ C, int layer) {
    __shared__ char sm[16384];
    int tid = threadIdx.x;
    int yb = blockIdx.y;
    int m0 = (layer == 0) ? yb * 128
                          : ((yb < 8) ? (yb * 512 + 384) : (MFWD + (yb - 8) * 128));
    int n0 = blockIdx.x * 128;
    const __bf16* Bt = (m0 >= MFWD) ? opTb : opTf;
    int w = tid >> 6, l = tid & 63;
    int wm = w >> 1, wn = w & 1, lm = l & 15, q = l >> 4;
    f32x4 acc[4][4];
    #pragma unroll
    for (int i = 0; i < 4; i++)
        #pragma unroll
        for (int j = 0; j < 4; j++) acc[i][j] = (f32x4)0.f;
    for (int k0 = 0; k0 < 512; k0 += 32) {
        #pragma unroll
        for (int i = 0; i < 2; i++) {
            int s = i * 256 + tid;
            ASYNC16(y2 + (size_t)(m0 + (s >> 2)) * 512 + k0 + (s & 3) * 8, sm + s * 16);
        }
        #pragma unroll
        for (int i = 0; i < 2; i++) {
            int s = i * 256 + tid;
            ASYNC16(Bt + (size_t)(n0 + (s >> 2)) * 512 + k0 + (s & 3) * 8, sm + 8192 + s * 16);
        }
        __syncthreads();
        bf16x8 af[4], bfr[4];
        #pragma unroll
        for (int mf = 0; mf < 4; mf++)
            af[mf] = *(const bf16x8*)(sm + (wm * 64 + mf * 16 + lm) * 64 + q * 16);
        #pragma unroll
        for (int nf = 0; nf < 4; nf++)
            bfr[nf] = *(const bf16x8*)(sm + 8192 + (wn * 64 + nf * 16 + lm) * 64 + q * 16);
        #pragma unroll
        for (int mf = 0; mf < 4; mf++)
            #pragma unroll
            for (int nf = 0; nf < 4; nf++)
                acc[mf][nf] = __builtin_amdgcn_mfma_f32_16x16x32_bf16(af[mf], bfr[nf], acc[mf][nf], 0, 0, 0);
        __syncthreads();
    }
    #pragma unroll
    for (int mf = 0; mf < 4; mf++) {
        int mbase = m0 + wm * 64 + mf * 16 + q * 4;
        #pragma unroll
        for (int nf = 0; nf < 4; nf++) {
            int n = n0 + wn * 64 + nf * 16 + lm;
            #pragma unroll
            for (int r = 0; r < 4; r++) {
                size_t ci = (size_t)(mbase + r) * DMODEL + n;
                C[ci] += acc[mf][nf][r];      // disjoint (m,n) tiles: no atomics
            }
        }
    }
}

// ---------------- elementwise norms (wave per row, 4 rows/block) ----------------
__global__ __launch_bounds__(256) void rmsnorm_all(
    const float* __restrict__ h, const float* __restrict__ wf,
    const float* __restrict__ wb, __bf16* __restrict__ u) {
    int row = blockIdx.x * 4 + (threadIdx.x >> 6);
    int lane = threadIdx.x & 63;
    const float* w = (row >= MFWD) ? wb : wf;
    float4 v = ((const float4*)(h + (size_t)row * 256))[lane];
    float ss = v.x * v.x + v.y * v.y + v.z * v.z + v.w * v.w;
    #pragma unroll
    for (int off = 32; off >= 1; off >>= 1) ss += __shfl_xor(ss, off);
    float rs = rsqrtf(ss * (1.f / 256.f) + 1e-5f);
    float4 wv = ((const float4*)w)[lane];
    __bf16 o4[4] = {(__bf16)(v.x * rs * wv.x), (__bf16)(v.y * rs * wv.y),
                    (__bf16)(v.z * rs * wv.z), (__bf16)(v.w * rs * wv.w)};
    *(uint2*)(u + (size_t)row * 256 + lane * 4) = *(uint2*)o4;
}

__global__ __launch_bounds__(256) void gatednorm_all(
    const __bf16* __restrict__ ysD, const float* __restrict__ zx,
    const float* __restrict__ gwf, const float* __restrict__ gwb,
    __bf16* __restrict__ y2) {
    int row = blockIdx.x * 4 + (threadIdx.x >> 6);
    int lane = threadIdx.x & 63;
    const float* gw = (row >= MFWD) ? gwb : gwf;
    union { uint4 u; __bf16 hh[8]; } yv;
    yv.u = *(const uint4*)(ysD + (size_t)row * 512 + lane * 8);
    const float4* zr = (const float4*)(zx + (size_t)row * DPROJ + lane * 8);
    float4 z0 = zr[0], z1 = zr[1];
    float g[8];
    g[0] = (float)yv.hh[0] * silu_f(z0.x); g[1] = (float)yv.hh[1] * silu_f(z0.y);
    g[2] = (float)yv.hh[2] * silu_f(z0.z); g[3] = (float)yv.hh[3] * silu_f(z0.w);
    g[4] = (float)yv.hh[4] * silu_f(z1.x); g[5] = (float)yv.hh[5] * silu_f(z1.y);
    g[6] = (float)yv.hh[6] * silu_f(z1.z); g[7] = (float)yv.hh[7] * silu_f(z1.w);
    float ss = 0.f;
    #pragma unroll
    for (int j = 0; j < 8; j++) ss += g[j] * g[j];
    #pragma unroll
    for (int off = 32; off >= 1; off >>= 1) ss += __shfl_xor(ss, off);
    float rs = rsqrtf(ss * (1.f / 512.f) + 1e-5f);
    const float4* gr = (const float4*)(gw + lane * 8);
    float4 g0 = gr[0], g1 = gr[1];
    union { uint4 u; __bf16 hh[8]; } d;
    d.hh[0] = (__bf16)(g[0] * rs * g0.x); d.hh[1] = (__bf16)(g[1] * rs * g0.y);
    d.hh[2] = (__bf16)(g[2] * rs * g0.z); d.hh[3] = (__bf16)(g[3] * rs * g0.w);
    d.hh[4] = (__bf16)(g[4] * rs * g1.x); d.hh[5] = (__bf16)(g[5] * rs * g1.y);
    d.hh[6] = (__bf16)(g[6] * rs * g1.z); d.hh[7] = (__bf16)(g[7] * rs * g1.w);
    *(uint4*)(y2 + (size_t)row * 512 + lane * 8) = d.u;
}

// ---------------- segmented prep kernel (all coalesced) ----------------
__global__ void prep_all(const float* __restrict__ pre_conv_w, const float* __restrict__ patch_w,
                         const float* __restrict__ ip0, const float* __restrict__ ip1,
                         const float* __restrict__ op0, const float* __restrict__ op1,
                         const float* __restrict__ pow_, const float* __restrict__ pob,
                         const float* __restrict__ y_aux, const float* __restrict__ aux_w,
                         const float* __restrict__ aux_b, const float* __restrict__ xp,
                         __bf16* __restrict__ WpreT, __bf16* __restrict__ WtT,
                         __bf16* __restrict__ inprojT, __bf16* __restrict__ outprojT,
                         __bf16* __restrict__ poT, float* __restrict__ auxb,
                         float* __restrict__ dout, __bf16* __restrict__ Aim) {
    __shared__ float tile[32][33];
    int bx = blockIdx.x, tid = threadIdx.x;
    int tx = tid & 31, ty = tid >> 5;
    if (bx < 256) {
        int o = bx, c = tid;
        float f[16];
        const float4* s = (const float4*)(patch_w + (size_t)o * 4096 + c * 16);
        #pragma unroll
        for (int j = 0; j < 4; j++) *(float4*)&f[j * 4] = s[j];
        #pragma unroll
        for (int k = 0; k < 16; k++)
            WtT[(size_t)o * 4096 + k * 256 + c] = (__bf16)f[k];
        return;
    }
    bx -= 256;
    if (bx < 1152) {
        int seg = bx / 288, rem = bx % 288;
        int n0 = (rem / 8) * 32, k0 = (rem % 8) * 32;
        const float* src = (seg < 2 ? ip0 : ip1) + (size_t)(seg & 1) * 256 * DPROJ;
        #pragma unroll
        for (int j = 0; j < 4; j++) {
            int r = ty + j * 8;
            int n = n0 + tx;
            tile[r][tx] = (n < DPROJ) ? src[(size_t)(k0 + r) * DPROJ + n] : 0.f;
        }
        __syncthreads();
        __bf16* dst = inprojT + (size_t)seg * 1152 * 256;
        #pragma unroll
        for (int j = 0; j < 4; j++) {
            int r = ty + j * 8;
            dst[(size_t)(n0 + r) * 256 + k0 + tx] = (__bf16)tile[tx][r];
        }
        return;
    }
    bx -= 1152;
    if (bx < 512) {
        int s = bx / 128, rem = bx % 128;
        int n0 = (rem / 16) * 32, k0 = (rem % 16) * 32;
        const float* src = (s < 2 ? op0 : op1) + (size_t)(s & 1) * DINNER * DMODEL;
        #pragma unroll
        for (int j = 0; j < 4; j++) {
            int r = ty + j * 8;
            tile[r][tx] = src[(size_t)(k0 + r) * 256 + n0 + tx];
        }
        __syncthreads();
        __bf16* dst = outprojT + (size_t)s * 256 * 512;
        #pragma unroll
        for (int j = 0; j < 4; j++) {
            int r = ty + j * 8;
            dst[(size_t)(n0 + r) * 512 + k0 + tx] = (__bf16)tile[tx][r];
        }
        return;
    }
    bx -= 512;
    if (bx < 64) {
        int n0 = (bx / 16) * 32, k0 = (bx % 16) * 32;
        #pragma unroll
        for (int j = 0; j < 4; j++) {
            int r = ty + j * 8;
            tile[r][tx] = pow_[(size_t)(k0 + r) * 128 + n0 + tx];
        }
        __syncthreads();
        #pragma unroll
        for (int j = 0; j < 4; j++) {
            int r = ty + j * 8;
            poT[(size_t)(n0 + r) * 512 + k0 + tx] = (__bf16)tile[tx][r];
        }
        return;
    }
    bx -= 64;
    if (bx < 64) {
        int idx = bx * 256 + tid;
        int o = idx >> 6, kk = idx & 63;
        WpreT[idx] = (kk < 40) ? (__bf16)pre_conv_w[o * 40 + kk] : (__bf16)0.f;
        return;
    }
    bx -= 64;
    if (bx < 512) {
        int idx = bx * 256 + tid;
        dout[idx] = pob[idx & 127];
        return;
    }
    bx -= 512;
    if (bx < 192) {
        int m = bx * 256 + tid;
        int t = m % TPREF, b = m / TPREF;
        __bf16 d[64];
        #pragma unroll
        for (int k = 0; k < 5; k++) {
            int tt = t - 2 + k;
            bool ok = (tt >= 0) && (tt < TPREF);
            const float* s = xp + ((size_t)b * TPREF + tt) * 8;
            #pragma unroll
            for (int i = 0; i < 8; i++)
                d[i * 5 + k] = ok ? (__bf16)s[i] : (__bf16)0.f;
        }
        #pragma unroll
        for (int j = 40; j < 64; j++) d[j] = (__bf16)0.f;
        uint4* o = (uint4*)(Aim + (size_t)m * 64);
        #pragma unroll
        for (int k = 0; k < 8; k++) o[k] = ((const uint4*)d)[k];
        return;
    }
    bx -= 192;
    {
        int b = bx, o = tid;
        float acc = aux_b[o];
        #pragma unroll
        for (int i = 0; i < 16; i++) acc += y_aux[b * 16 + i] * aux_w[i * 256 + o];
        auxb[b * 256 + o] = silu_f(acc);
    }
}

// assemble: sum 4 patch partials + bias, build h_all
__global__ void assemble_kernel(const float* __restrict__ Cp4, const float* __restrict__ pb,
                                const float* __restrict__ mtok, const float* __restrict__ aux,
                                float* __restrict__ h_all) {
    int idx = blockIdx.x * 256 + threadIdx.x;
    if (idx >= BSZ * NTOK * DMODEL) return;
    int o = idx & 255, tok = (idx >> 8) & 511, b = idx >> 17;
    float v;
    if (tok < NVIS) {
        size_t ci = (size_t)(b * NVIS + tok) * 256 + o;
        v = pb[o] + Cp4[ci] + Cp4[ci + (size_t)3072 * 256] +
            Cp4[ci + (size_t)2 * 3072 * 256] + Cp4[ci + (size_t)3 * 3072 * 256];
    } else {
        v = mtok[o];
    }
    v += aux[b * 256 + o];
    h_all[idx] = v;
    if (tok >= NVIS)
        h_all[(size_t)MFWD * 256 + (size_t)(b * TBWD + (NTOK - 1 - tok)) * 256 + o] = v;
}

// causal depthwise conv (k=4) + bias + silu; fwd+bwd batched. grid (9, 80)
__global__ __launch_bounds__(256) void dwconv2_kernel(
    const float* __restrict__ zx, const float* __restrict__ cwf, const float* __restrict__ cbf,
    const float* __restrict__ cwb, const float* __restrict__ cbb,
    __bf16* __restrict__ XtF, __bf16* __restrict__ XtB,
    __bf16* __restrict__ BCF, __bf16* __restrict__ BCB) {
    int cg = blockIdx.x;
    int id = blockIdx.y;
    int b, t0, T; size_t rowbase;
    const float *cw, *cb; __bf16 *Xt, *BC;
    if (id < 64) { b = id >> 3; t0 = (id & 7) * 64; T = NTOK; rowbase = (size_t)b * NTOK;
                   cw = cwf; cb = cbf; Xt = XtF; BC = BCF; }
    else { int i2 = id - 64; b = i2 >> 1; t0 = (i2 & 1) * 64; T = TBWD;
           rowbase = (size_t)MFWD + (size_t)b * TBWD; cw = cwb; cb = cbb; Xt = XtB; BC = BCB; }
    int c0 = cg * 64;
    __shared__ float xs[67][65];
    int lane = threadIdx.x & 63, grp = threadIdx.x >> 6;
    for (int r = grp; r < 67; r += 4) {
        int t = t0 - 3 + r;
        xs[r][lane] = (t >= 0) ? zx[(rowbase + t) * DPROJ + DINNER + c0 + lane] : 0.f;
    }
    __syncthreads();
    if (cg < 8) {
        int t = lane;
        #pragma unroll
        for (int ci = grp; ci < 64; ci += 4) {
            int c = c0 + ci;
            float acc = cb[c];
            #pragma unroll
            for (int k = 0; k < 4; k++) acc += cw[c * 4 + k] * xs[t + k][ci];
            Xt[((size_t)((b * 8 + cg) * 64 + ci)) * T + t0 + t] = (__bf16)silu_f(acc);
        }
    } else {
        int c = lane;
        #pragma unroll
        for (int ti = grp; ti < 64; ti += 4) {
            float acc = cb[c0 + c];
            #pragma unroll
            for (int k = 0; k < 4; k++) acc += cw[(c0 + c) * 4 + k] * xs[ti + k][c];
            BC[((size_t)(b * T + t0 + ti)) * 64 + c] = (__bf16)silu_f(acc);
        }
    }
}

// ---------------- chunked SSD scan phase A (fwd+bwd batched, layer-aware). grid (80, 8) ----------------
__global__ __launch_bounds__(64) void scan_local(
    const __bf16* __restrict__ XtF, const __bf16* __restrict__ XtB,
    const __bf16* __restrict__ BCF, const __bf16* __restrict__ BCB,
    const float* __restrict__ zx,
    const float* __restrict__ dtbf, const float* __restrict__ dtbb,
    const float* __restrict__ Alogf, const float* __restrict__ Alogb,
    const float* __restrict__ Dpf, const float* __restrict__ Dpb,
    __bf16* __restrict__ ysD,
    __bf16* __restrict__ ChatF, __bf16* __restrict__ ChatB,
    float* __restrict__ dSF, float* __restrict__ dSB,
    float* __restrict__ DcsF, float* __restrict__ DcsB, int layer) {
    int id = blockIdx.x, hd = blockIdx.y;
    int b, c, T, NC; size_t rowbase;
    const __bf16 *Xt, *BC; __bf16* Chat; float *dS, *Dcs;
    const float *dtb, *Alog, *Dp;
    if (id < 64) { b = id >> 3; c = id & 7; T = NTOK; NC = 8; rowbase = (size_t)b * NTOK;
                   Xt = XtF; BC = BCF; Chat = ChatF; dS = dSF; Dcs = DcsF;
                   dtb = dtbf; Alog = Alogf; Dp = Dpf; }
    else { int i2 = id - 64; b = i2 >> 1; c = i2 & 1; T = TBWD; NC = 2;
           rowbase = (size_t)MFWD + (size_t)b * TBWD;
           Xt = XtB; BC = BCB; Chat = ChatB; dS = dSB; Dcs = DcsB;
           dtb = dtbb; Alog = Alogb; Dp = Dpb; }
    bool skipY = (layer == 1) && (id < 64) && (c < 6);   // layer-2 fwd t<384: Y unused
    int bh = b * 8 + hd;
    int t0 = c * 64;
    int lane = threadIdx.x;
    int lm = lane & 15, q = lane >> 4;
    float A = -expf(Alog[hd]);
    float Dh = Dp[hd];

    __shared__ char smem[23552];
    __bf16 (*Xl)[72]  = (__bf16(*)[72])(smem);
    __bf16 (*BCl)[72] = (__bf16(*)[72])(smem + 9216);
    __bf16 (*Pl)[72]  = (__bf16(*)[72])(smem + 9216);
    __bf16 (*Wbl)[72] = (__bf16(*)[72])(smem + 18432);
    float* lcs = (float*)(smem + 23040);
    float* dts = (float*)(smem + 23296);

    const uint4* xg = (const uint4*)(Xt + (size_t)(bh * 64 + lane) * T + t0);
    const uint4* bg = (const uint4*)(BC + ((size_t)(b * T + t0 + lane)) * 64);
    uint4 xv[8], bv[8];
    #pragma unroll
    for (int k = 0; k < 8; k++) { xv[k] = xg[k]; bv[k] = bg[k]; }
    float xdt = zx[(rowbase + t0 + lane) * DPROJ + 1088 + hd] + dtb[hd];
    float dtv = (xdt > 20.f) ? xdt : log1pf(expf(xdt));
    #pragma unroll
    for (int k = 0; k < 8; k++) {
        *(uint4*)&Xl[lane][k * 8] = xv[k];
        if (!skipY) *(uint4*)&BCl[lane][k * 8] = bv[k];
    }
    float lc = A * dtv;
    #pragma unroll
    for (int off = 1; off < 64; off <<= 1) {
        float o = __shfl_up(lc, off);
        if (lane >= off) lc += o;
    }
    lcs[lane] = lc; dts[lane] = dtv;
    float lc63 = __shfl(lc, 63);
    float wj = expf(lc63 - lc) * dtv;
    float eli = expf(lc);
    float Dc = expf(lc63);
    if (lane == 0) Dcs[bh * NC + c] = Dc;
    if (!skipY) {
        __bf16* co = Chat + ((size_t)(bh * NC + c) * 64 + lane) * 32;
        #pragma unroll
        for (int k = 0; k < 4; k++) {
            union { uint4 u; __bf16 h[8]; } s; s.u = bv[4 + k];
            union { uint4 u; __bf16 h[8]; } d;
            #pragma unroll
            for (int j = 0; j < 8; j++) d.h[j] = (__bf16)(eli * (float)s.h[j]);
            *(uint4*)(co + k * 8) = d.u;
        }
    }
    #pragma unroll
    for (int k = 0; k < 4; k++) {
        union { uint4 u; __bf16 h[8]; } s; s.u = bv[k];
        #pragma unroll
        for (int j = 0; j < 8; j++) Wbl[k * 8 + j][lane] = (__bf16)(wj * (float)s.h[j]);
    }
    __syncthreads();

    bf16x8 xf0[4], xf1[4];
    if (!skipY) {
        bf16x8 cfr[4], bfr[4];
        #pragma unroll
        for (int t4 = 0; t4 < 4; t4++) {
            cfr[t4] = *(const bf16x8*)&BCl[t4 * 16 + lm][32 + q * 8];
            bfr[t4] = *(const bf16x8*)&BCl[t4 * 16 + lm][q * 8];
        }
        #pragma unroll
        for (int ti = 0; ti < 4; ti++) {
            float lci[4];
            #pragma unroll
            for (int r = 0; r < 4; r++) lci[r] = lcs[ti * 16 + q * 4 + r];
            #pragma unroll
            for (int tj = 0; tj < 4; tj++) {
                if (tj > ti) {
                    #pragma unroll
                    for (int r = 0; r < 4; r++) Pl[ti * 16 + q * 4 + r][tj * 16 + lm] = (__bf16)0.f;
                    continue;
                }
                f32x4 g = __builtin_amdgcn_mfma_f32_16x16x32_bf16(cfr[ti], bfr[tj], (f32x4)0.f, 0, 0, 0);
                int j = tj * 16 + lm;
                float lcj = lcs[j], dtj = dts[j];
                #pragma unroll
                for (int r = 0; r < 4; r++) {
                    int i = ti * 16 + q * 4 + r;
                    float v = (j <= i) ? g[r] * expf(lci[r] - lcj) * dtj : 0.f;
                    if (j == i) v += Dh;
                    Pl[i][j] = (__bf16)v;
                }
            }
        }
        __syncthreads();

        bf16x8 pf0[4], pf1[4];
        #pragma unroll
        for (int t4 = 0; t4 < 4; t4++) {
            pf0[t4] = *(const bf16x8*)&Pl[t4 * 16 + lm][q * 8];
            pf1[t4] = *(const bf16x8*)&Pl[t4 * 16 + lm][32 + q * 8];
            xf0[t4] = *(const bf16x8*)&Xl[t4 * 16 + lm][q * 8];
            xf1[t4] = *(const bf16x8*)&Xl[t4 * 16 + lm][32 + q * 8];
        }
        #pragma unroll
        for (int ti = 0; ti < 4; ti++) {
            #pragma unroll
            for (int tp = 0; tp < 4; tp++) {
                f32x4 y = __builtin_amdgcn_mfma_f32_16x16x32_bf16(pf0[ti], xf0[tp], (f32x4)0.f, 0, 0, 0);
                y = __builtin_amdgcn_mfma_f32_16x16x32_bf16(pf1[ti], xf1[tp], y, 0, 0, 0);
                #pragma unroll
                for (int r = 0; r < 4; r++) {
                    int i = ti * 16 + q * 4 + r;
                    ysD[(rowbase + t0 + i) * DINNER + hd * 64 + tp * 16 + lm] = (__bf16)y[r];
                }
            }
        }
    } else {
        #pragma unroll
        for (int t4 = 0; t4 < 4; t4++) {
            xf0[t4] = *(const bf16x8*)&Xl[t4 * 16 + lm][q * 8];
            xf1[t4] = *(const bf16x8*)&Xl[t4 * 16 + lm][32 + q * 8];
        }
    }
    bf16x8 wf0[2], wf1[2];
    #pragma unroll
    for (int tn = 0; tn < 2; tn++) {
        wf0[tn] = *(const bf16x8*)&Wbl[tn * 16 + lm][q * 8];
        wf1[tn] = *(const bf16x8*)&Wbl[tn * 16 + lm][32 + q * 8];
    }
    float* dso = dS + (size_t)(bh * NC + c) * 2048;
    #pragma unroll
    for (int tp = 0; tp < 4; tp++) {
        #pragma unroll
        for (int tn = 0; tn < 2; tn++) {
            f32x4 s = __builtin_amdgcn_mfma_f32_16x16x32_bf16(xf0[tp], wf0[tn], (f32x4)0.f, 0, 0, 0);
            s = __builtin_amdgcn_mfma_f32_16x16x32_bf16(xf1[tp], wf1[tn], s, 0, 0, 0);
            #pragma unroll
            for (int r = 0; r < 4; r++) {
                int pp = tp * 16 + q * 4 + r, nn = tn * 16 + lm;
                dso[pp * 32 + nn] = s[r];
            }
        }
    }
}

// ---------------- scan tail (batched, layer-aware): recurrence + cross-chunk Y add ----------------
__global__ __launch_bounds__(256) void scan_tail(
    const float* __restrict__ dSF, const float* __restrict__ dSB,
    const float* __restrict__ DcsF, const float* __restrict__ DcsB,
    const __bf16* __restrict__ ChatF, const __bf16* __restrict__ ChatB,
    __bf16* __restrict__ ysD, int layer) {
    int blk = blockIdx.x;
    int dir = blk >= 64;
    int bh = blk & 63;
    int NC = dir ? 2 : 8;
    int T = dir ? TBWD : NTOK;
    int b = bh >> 3, hd = bh & 7;
    size_t rowbase = dir ? ((size_t)MFWD + (size_t)b * TBWD) : ((size_t)b * NTOK);
    const float* dS = dir ? dSB : dSF;
    const float* Dcs = dir ? DcsB : DcsF;
    const __bf16* Chat = dir ? ChatB : ChatF;
    int cmin = (layer == 1 && !dir) ? 6 : 1;
    int tid = threadIdx.x;
    __shared__ __bf16 Spl[8][64][40];
    {
        int p = tid >> 2, n0 = (tid & 3) * 8;
        float S[8];
        #pragma unroll
        for (int j = 0; j < 8; j++) S[j] = 0.f;
        for (int c = 0; c < NC; c++) {
            union { uint4 u; __bf16 hh[8]; } o;
            #pragma unroll
            for (int j = 0; j < 8; j++) o.hh[j] = (__bf16)S[j];
            *(uint4*)&Spl[c][p][n0] = o.u;
            float Dc = Dcs[bh * NC + c];
            const float4* dp = (const float4*)(dS + ((size_t)(bh * NC + c)) * 2048 + tid * 8);
            float4 d0 = dp[0], d1 = dp[1];
            S[0] = Dc * S[0] + d0.x; S[1] = Dc * S[1] + d0.y;
            S[2] = Dc * S[2] + d0.z; S[3] = Dc * S[3] + d0.w;
            S[4] = Dc * S[4] + d1.x; S[5] = Dc * S[5] + d1.y;
            S[6] = Dc * S[6] + d1.z; S[7] = Dc * S[7] + d1.w;
        }
    }
    __syncthreads();
    int w = tid >> 6, l = tid & 63, lm = l & 15, q = l >> 4;
    for (int c = cmin + w; c < NC; c += 4) {
        int t0 = c * 64;
        const __bf16* Cb = Chat + (size_t)(bh * NC + c) * 2048;
        bf16x8 cf[4], sf[4];
        #pragma unroll
        for (int t4 = 0; t4 < 4; t4++) {
            cf[t4] = *(const bf16x8*)(Cb + (t4 * 16 + lm) * 32 + q * 8);
            sf[t4] = *(const bf16x8*)&Spl[c][t4 * 16 + lm][q * 8];
        }
        #pragma unroll
        for (int ti = 0; ti < 4; ti++) {
            #pragma unroll
            for (int tp = 0; tp < 4; tp++) {
                f32x4 y = __builtin_amdgcn_mfma_f32_16x16x32_bf16(cf[ti], sf[tp], (f32x4)0.f, 0, 0, 0);
                #pragma unroll
                for (int r = 0; r < 4; r++) {
                    int i = ti * 16 + q * 4 + r;
                    size_t idx = (rowbase + t0 + i) * DINNER + hd * 64 + tp * 16 + lm;
                    ysD[idx] = (__bf16)((float)ysD[idx] + y[r]);
                }
            }
        }
    }
}

__global__ void hcat_kernel(const float* __restrict__ h_all, __bf16* __restrict__ hc) {
    int idx = blockIdx.x * 256 + threadIdx.x;
    if (idx >= BSZ * TBWD * DINNER) return;
    int c = idx & 511, j = (idx >> 9) & 127, b = idx >> 16;
    float v = (c < 256) ? h_all[(size_t)(b * NTOK + NVIS + j) * 256 + c]
                        : h_all[(size_t)MFWD * 256 + (size_t)(b * TBWD + (TBWD - 1 - j)) * 256 + (c - 256)];
    hc[idx] = (__bf16)v;
}

// ---------------- launch ----------------
extern "C" void kernel_launch(void* const* d_in, const int* in_sizes, int n_in,
                              void* d_out, int out_size, void* d_ws, size_t ws_size,
                              hipStream_t stream) {
    const float* x_prefix    = (const float*)d_in[0];
    const float* y_aux       = (const float*)d_in[1];
    const float* pre_conv_w  = (const float*)d_in[2];
    const float* pre_conv_b  = (const float*)d_in[3];
    const float* patch_w     = (const float*)d_in[4];
    const float* patch_b     = (const float*)d_in[5];
    const float* mask_token  = (const float*)d_in[6];
    const float* aux_w       = (const float*)d_in[7];
    const float* aux_b       = (const float*)d_in[8];
    const float* patch_out_w = (const float*)d_in[9];
    const float* patch_out_b = (const float*)d_in[10];
    const float* w_norm[2]   = {(const float*)d_in[11], (const float*)d_in[20]};
    const float* w_inproj[2] = {(const float*)d_in[12], (const float*)d_in[21]};
    const float* w_convw[2]  = {(const float*)d_in[13], (const float*)d_in[22]};
    const float* w_convb[2]  = {(const float*)d_in[14], (const float*)d_in[23]};
    const float* w_dtb[2]    = {(const float*)d_in[15], (const float*)d_in[24]};
    const float* w_alog[2]   = {(const float*)d_in[16], (const float*)d_in[25]};
    const float* w_D[2]      = {(const float*)d_in[17], (const float*)d_in[26]};
    const float* w_gnorm[2]  = {(const float*)d_in[18], (const float*)d_in[27]};
    const float* w_outproj[2]= {(const float*)d_in[19], (const float*)d_in[28]};

    char* p = (char*)d_ws;
    auto alloc = [&](size_t bytes) { char* r = p; p += (bytes + 255) & ~255ULL; return r; };
    __bf16* A_patch  = (__bf16*)alloc((size_t)3072 * 4096 * 2);
    __bf16* Aim      = (__bf16*)alloc((size_t)BSZ * TPREF * 64 * 2);
    __bf16* WpreT    = (__bf16*)alloc((size_t)256 * 64 * 2);
    __bf16* WtT      = (__bf16*)alloc((size_t)256 * 4096 * 2);
    __bf16* inprojT  = (__bf16*)alloc((size_t)4 * 1152 * 256 * 2);
    __bf16* outprojT = (__bf16*)alloc((size_t)4 * 256 * 512 * 2);
    __bf16* poT      = (__bf16*)alloc((size_t)128 * 512 * 2);
    float*  auxb     = (float*)alloc(8 * 256 * 4);
    float*  Cp4      = (float*)alloc((size_t)4 * 3072 * 256 * 4);
    float*  h_all    = (float*)alloc((size_t)MALL * 256 * 4);
    __bf16* u        = (__bf16*)alloc((size_t)MALL * 256 * 2);
    float*  zx       = (float*)alloc((size_t)MALL * DPROJ * 4);
    __bf16* XtF      = (__bf16*)alloc((size_t)64 * 64 * NTOK * 2);
    __bf16* XtB      = (__bf16*)alloc((size_t)64 * 64 * TBWD * 2);
    __bf16* BCF      = (__bf16*)alloc((size_t)BSZ * NTOK * 64 * 2);
    __bf16* BCB      = (__bf16*)alloc((size_t)BSZ * TBWD * 64 * 2);
    __bf16* ysD      = (__bf16*)alloc((size_t)MALL * DINNER * 2);
    __bf16* y2       = (__bf16*)alloc((size_t)MALL * DINNER * 2);
    __bf16* hct      = (__bf16*)alloc((size_t)1024 * DINNER * 2);
    __bf16* ChatF    = (__bf16*)alloc((size_t)64 * 8 * 2048 * 2);
    __bf16* ChatB    = (__bf16*)alloc((size_t)64 * 2 * 2048 * 2);
    float*  dSF      = (float*)alloc((size_t)64 * 8 * 2048 * 4);
    float*  dSB      = (float*)alloc((size_t)64 * 2 * 2048 * 4);
    float*  DcsF     = (float*)alloc((size_t)64 * 8 * 4);
    float*  DcsB     = (float*)alloc((size_t)64 * 2 * 4);

    prep_all<<<256 + 1152 + 512 + 64 + 64 + 512 + 192 + 8, 256, 0, stream>>>(
        pre_conv_w, patch_w, w_inproj[0], w_inproj[1], w_outproj[0], w_outproj[1],
        patch_out_w, patch_out_b, y_aux, aux_w, aux_b, x_prefix,
        WpreT, WtT, inprojT, outprojT, poT, auxb, (float*)d_out, Aim);
    gemm_mfma<<<dim3(2, (BSZ * TPREF) / 128, 1), 256, 0, stream>>>(
        Aim, WpreT, (float*)A_patch, pre_conv_b, 256, 64, 256, 4, 0);
    gemm_mfma<<<dim3(2, 24, 4), 256, 0, stream>>>(
        A_patch, WtT, Cp4, nullptr, 256, 4096, 256, 8, (long)3072 * 256);
    assemble_kernel<<<(BSZ * NTOK * DMODEL) / 256, 256, 0, stream>>>(
        Cp4, patch_b, mask_token, auxb, h_all);

    for (int i = 0; i < 2; i++) {
        const __bf16* ipTf = inprojT + (size_t)(0 * 2 + i) * 1152 * 256;
        const __bf16* ipTb = inprojT + (size_t)(1 * 2 + i) * 1152 * 256;
        const __bf16* opTf = outprojT + (size_t)(0 * 2 + i) * 256 * 512;
        const __bf16* opTb = outprojT + (size_t)(1 * 2 + i) * 256 * 512;
        rmsnorm_all<<<MALL / 4, 256, 0, stream>>>(h_all, w_norm[0] + i * 256, w_norm[1] + i * 256, u);
        gemm_inproj<<<dim3(9, MALL / 128), 256, 0, stream>>>(u, ipTf, ipTb, zx);
        dwconv2_kernel<<<dim3(9, 80), 256, 0, stream>>>(
            zx, w_convw[0] + i * CONVDIM * 4, w_convb[0] + i * CONVDIM,
            w_convw[1] + i * CONVDIM * 4, w_convb[1] + i * CONVDIM,
            XtF, XtB, BCF, BCB);
        scan_local<<<dim3(80, NHEADS), 64, 0, stream>>>(
            XtF, XtB, BCF, BCB, zx,
            w_dtb[0] + i * 8, w_dtb[1] + i * 8,
            w_alog[0] + i * 8, w_alog[1] + i * 8,
            w_D[0] + i * 8, w_D[1] + i * 8,
            ysD, ChatF, ChatB, dSF, dSB, DcsF, DcsB, i);
        scan_tail<<<128, 256, 0, stream>>>(dSF, dSB, DcsF, DcsB, ChatF, ChatB, ysD, i);
        gatednorm_all<<<MALL / 4, 256, 0, stream>>>(
            ysD, zx, w_gnorm[0] + i * DINNER, w_gnorm[1] + i * DINNER, y2);
        int oy = (i == 0) ? (MALL / 128) : 16;
        gemm_outproj<<<dim3(2, oy), 256, 0, stream>>>(y2, opTf, opTb, h_all, i);
    }

    hcat_kernel<<<(BSZ * TBWD * DINNER) / 256, 256, 0, stream>>>(h_all, hct);
    gemm_mfma<<<dim3(1, 8, 4), 256, 0, stream>>>(
        hct, poT, (float*)d_out, nullptr, 128, 512, 128, 2, 0);
}

// Round 10
// 338.481 us; speedup vs baseline: 1.3203x; 1.0033x over previous
//
#include <hip/hip_runtime.h>
#include <hip/hip_bf16.h>
#include <math.h>

// ---------------- constants ----------------
#define BSZ      8
#define TPREF    6144
#define CIN      8
#define DMODEL   256
#define DINNER   512
#define DSTATE   32
#define NHEADS   8
#define HEADDIM  64
#define CONVDIM  576
#define DPROJ    1096
#define ZXW      1088              // bf16 zx width (z 0..511 | xBC 512..1087)
#define NTOK     512
#define NVIS     384
#define TBWD     128
#define MFWD     (BSZ * NTOK)      // 4096 rows
#define MBWD     (BSZ * TBWD)      // 1024 rows
#define MALL     (MFWD + MBWD)     // 5120 rows

typedef float f32x4 __attribute__((ext_vector_type(4)));
typedef __bf16 bf16x8 __attribute__((ext_vector_type(8)));

__device__ __forceinline__ float silu_f(float x) { return x / (1.f + expf(-x)); }

#define ASYNC16(gp, lp) \
    __builtin_amdgcn_global_load_lds((const __attribute__((address_space(1))) void*)(gp), \
                                     (__attribute__((address_space(3))) void*)(lp), 16, 0, 0)

// ---------------- generic bf16 MFMA GEMM (NT): C[m,n] = sum_k A[m,k]*Bt[n,k] ----------------
// flags: 2=atomicAdd; 4=silu(v+bias)+bf16 store; 16=atomicAdd into h_all with (b,tok)->row remap
__global__ __launch_bounds__(256) void gemm_mfma(
    const __bf16* __restrict__ A, const __bf16* __restrict__ Bt,
    float* __restrict__ C, const float* __restrict__ bias,
    int N, int K, int ldc, int flags) {
    __shared__ char sm[16384];
    int tid = threadIdx.x;
    int m0 = blockIdx.y * 128, n0 = blockIdx.x * 128;
    int klen = K / gridDim.z;
    int kbeg = blockIdx.z * klen;
    int w = tid >> 6, l = tid & 63;
    int wm = w >> 1, wn = w & 1;
    int lm = l & 15, q = l >> 4;

    f32x4 acc[4][4];
    #pragma unroll
    for (int i = 0; i < 4; i++)
        #pragma unroll
        for (int j = 0; j < 4; j++) acc[i][j] = (f32x4)0.f;

    for (int k0 = 0; k0 < klen; k0 += 32) {
        int kb = kbeg + k0;
        #pragma unroll
        for (int i = 0; i < 2; i++) {
            int s = i * 256 + tid;
            ASYNC16(A + (size_t)(m0 + (s >> 2)) * K + kb + (s & 3) * 8, sm + s * 16);
        }
        #pragma unroll
        for (int i = 0; i < 2; i++) {
            int s = i * 256 + tid;
            ASYNC16(Bt + (size_t)(n0 + (s >> 2)) * K + kb + (s & 3) * 8, sm + 8192 + s * 16);
        }
        __syncthreads();
        bf16x8 af[4], bfr[4];
        #pragma unroll
        for (int mf = 0; mf < 4; mf++)
            af[mf] = *(const bf16x8*)(sm + (wm * 64 + mf * 16 + lm) * 64 + q * 16);
        #pragma unroll
        for (int nf = 0; nf < 4; nf++)
            bfr[nf] = *(const bf16x8*)(sm + 8192 + (wn * 64 + nf * 16 + lm) * 64 + q * 16);
        #pragma unroll
        for (int mf = 0; mf < 4; mf++)
            #pragma unroll
            for (int nf = 0; nf < 4; nf++)
                acc[mf][nf] = __builtin_amdgcn_mfma_f32_16x16x32_bf16(af[mf], bfr[nf], acc[mf][nf], 0, 0, 0);
        __syncthreads();
    }

    #pragma unroll
    for (int mf = 0; mf < 4; mf++) {
        int mbase = m0 + wm * 64 + mf * 16 + q * 4;
        #pragma unroll
        for (int nf = 0; nf < 4; nf++) {
            int n = n0 + wn * 64 + nf * 16 + lm;
            if (n < N) {
                #pragma unroll
                for (int r = 0; r < 4; r++) {
                    float v = acc[mf][nf][r];
                    if (flags & 4) {
                        v = silu_f(v + bias[n]);
                        ((__bf16*)C)[(size_t)(mbase + r) * ldc + n] = (__bf16)v;
                    } else if (flags & 16) {
                        int mm = mbase + r;
                        int bb = mm / NVIS, tk = mm - bb * NVIS;   // m = b*384+tok
                        atomicAdd(C + ((size_t)(bb * NTOK + tk)) * 256 + n, v);
                    } else if (flags & 2) {
                        atomicAdd(C + (size_t)(mbase + r) * ldc + n, v);
                    } else {
                        C[(size_t)(mbase + r) * ldc + n] = v;
                    }
                }
            }
        }
    }
}

// ---------------- final GEMM: hcat gather fused; split-K 2 (z=0 fwd half, z=1 bwd half) ----------------
__global__ __launch_bounds__(256) void final_gemm(
    const float* __restrict__ h_all, const __bf16* __restrict__ poT,
    float* __restrict__ out) {
    __shared__ __bf16 Asm_[128][40];
    __shared__ char Bsm[8192];
    int tid = threadIdx.x;
    int m0 = blockIdx.y * 128;
    int z = blockIdx.z;
    int w = tid >> 6, l = tid & 63;
    int wm = w >> 1, wn_ = w & 1, lm = l & 15, q = l >> 4;
    f32x4 acc[4][4];
    #pragma unroll
    for (int i = 0; i < 4; i++)
        #pragma unroll
        for (int j = 0; j < 4; j++) acc[i][j] = (f32x4)0.f;

    int r = tid >> 1, half = tid & 1;
    int m = m0 + r;
    int b = m >> 7, jj = m & 127;
    size_t arow = (z == 0) ? ((size_t)(b * NTOK + NVIS + jj) * 256)
                           : ((size_t)MFWD * 256 + (size_t)(b * TBWD + (TBWD - 1 - jj)) * 256);
    for (int k0 = 0; k0 < 256; k0 += 32) {
        {
            const float4* sp = (const float4*)(h_all + arow + k0 + half * 16);
            float4 v0 = sp[0], v1 = sp[1], v2 = sp[2], v3 = sp[3];
            union { uint4 u; __bf16 hh[8]; } d0, d1;
            d0.hh[0] = (__bf16)v0.x; d0.hh[1] = (__bf16)v0.y; d0.hh[2] = (__bf16)v0.z; d0.hh[3] = (__bf16)v0.w;
            d0.hh[4] = (__bf16)v1.x; d0.hh[5] = (__bf16)v1.y; d0.hh[6] = (__bf16)v1.z; d0.hh[7] = (__bf16)v1.w;
            d1.hh[0] = (__bf16)v2.x; d1.hh[1] = (__bf16)v2.y; d1.hh[2] = (__bf16)v2.z; d1.hh[3] = (__bf16)v2.w;
            d1.hh[4] = (__bf16)v3.x; d1.hh[5] = (__bf16)v3.y; d1.hh[6] = (__bf16)v3.z; d1.hh[7] = (__bf16)v3.w;
            *(uint4*)&Asm_[r][half * 16] = d0.u;
            *(uint4*)&Asm_[r][half * 16 + 8] = d1.u;
        }
        #pragma unroll
        for (int i = 0; i < 2; i++) {
            int s = i * 256 + tid;
            ASYNC16(poT + (size_t)(s >> 2) * 512 + z * 256 + k0 + (s & 3) * 8, Bsm + s * 16);
        }
        __syncthreads();
        bf16x8 af[4], bfr[4];
        #pragma unroll
        for (int mf = 0; mf < 4; mf++)
            af[mf] = *(const bf16x8*)&Asm_[wm * 64 + mf * 16 + lm][q * 8];
        #pragma unroll
        for (int nf = 0; nf < 4; nf++)
            bfr[nf] = *(const bf16x8*)(Bsm + (wn_ * 64 + nf * 16 + lm) * 64 + q * 16);
        #pragma unroll
        for (int mf = 0; mf < 4; mf++)
            #pragma unroll
            for (int nf = 0; nf < 4; nf++)
                acc[mf][nf] = __builtin_amdgcn_mfma_f32_16x16x32_bf16(af[mf], bfr[nf], acc[mf][nf], 0, 0, 0);
        __syncthreads();
    }
    #pragma unroll
    for (int mf = 0; mf < 4; mf++) {
        int mbase = m0 + wm * 64 + mf * 16 + q * 4;
        #pragma unroll
        for (int nf = 0; nf < 4; nf++) {
            int n = wn_ * 64 + nf * 16 + lm;
            #pragma unroll
            for (int rr = 0; rr < 4; rr++)
                atomicAdd(out + (size_t)(mbase + rr) * 128 + n, acc[mf][nf][rr]);
        }
    }
}

// ---------------- inproj GEMM: 128x128 tile, K=256; bf16 zxb + fp32 dtc outputs ----------------
__global__ __launch_bounds__(256) void gemm_inproj(
    const __bf16* __restrict__ u, const __bf16* __restrict__ ipTf,
    const __bf16* __restrict__ ipTb, __bf16* __restrict__ zxb, float* __restrict__ dtc) {
    __shared__ char sm[16384];
    int tid = threadIdx.x;
    int m0 = blockIdx.y * 128, n0 = blockIdx.x * 128;
    const __bf16* Bt = (m0 >= MFWD) ? ipTb : ipTf;
    int w = tid >> 6, l = tid & 63;
    int wm = w >> 1, wn = w & 1, lm = l & 15, q = l >> 4;
    f32x4 acc[4][4];
    #pragma unroll
    for (int i = 0; i < 4; i++)
        #pragma unroll
        for (int j = 0; j < 4; j++) acc[i][j] = (f32x4)0.f;
    for (int k0 = 0; k0 < 256; k0 += 32) {
        #pragma unroll
        for (int i = 0; i < 2; i++) {
            int s = i * 256 + tid;
            ASYNC16(u + (size_t)(m0 + (s >> 2)) * 256 + k0 + (s & 3) * 8, sm + s * 16);
        }
        #pragma unroll
        for (int i = 0; i < 2; i++) {
            int s = i * 256 + tid;
            ASYNC16(Bt + (size_t)(n0 + (s >> 2)) * 256 + k0 + (s & 3) * 8, sm + 8192 + s * 16);
        }
        __syncthreads();
        bf16x8 af[4], bfr[4];
        #pragma unroll
        for (int mf = 0; mf < 4; mf++)
            af[mf] = *(const bf16x8*)(sm + (wm * 64 + mf * 16 + lm) * 64 + q * 16);
        #pragma unroll
        for (int nf = 0; nf < 4; nf++)
            bfr[nf] = *(const bf16x8*)(sm + 8192 + (wn * 64 + nf * 16 + lm) * 64 + q * 16);
        #pragma unroll
        for (int mf = 0; mf < 4; mf++)
            #pragma unroll
            for (int nf = 0; nf < 4; nf++)
                acc[mf][nf] = __builtin_amdgcn_mfma_f32_16x16x32_bf16(af[mf], bfr[nf], acc[mf][nf], 0, 0, 0);
        __syncthreads();
    }
    #pragma unroll
    for (int mf = 0; mf < 4; mf++) {
        int mbase = m0 + wm * 64 + mf * 16 + q * 4;
        #pragma unroll
        for (int nf = 0; nf < 4; nf++) {
            int n = n0 + wn * 64 + nf * 16 + lm;
            #pragma unroll
            for (int r = 0; r < 4; r++) {
                float v = acc[mf][nf][r];
                if (n < ZXW) zxb[(size_t)(mbase + r) * ZXW + n] = (__bf16)v;
                else if (n < DPROJ) dtc[(size_t)(mbase + r) * 8 + (n - ZXW)] = v;
            }
        }
    }
}

// ---------------- outproj GEMM: 128x128 tile, K=512, layer-aware rows, residual += ----------------
__global__ __launch_bounds__(256) void gemm_outproj(
    const __bf16* __restrict__ y2, const __bf16* __restrict__ opTf,
    const __bf16* __restrict__ opTb, float* __restrict__ C, int layer) {
    __shared__ char sm[16384];
    int tid = threadIdx.x;
    int yb = blockIdx.y;
    int m0 = (layer == 0) ? yb * 128
                          : ((yb < 8) ? (yb * 512 + 384) : (MFWD + (yb - 8) * 128));
    int n0 = blockIdx.x * 128;
    const __bf16* Bt = (m0 >= MFWD) ? opTb : opTf;
    int w = tid >> 6, l = tid & 63;
    int wm = w >> 1, wn = w & 1, lm = l & 15, q = l >> 4;
    f32x4 acc[4][4];
    #pragma unroll
    for (int i = 0; i < 4; i++)
        #pragma unroll
        for (int j = 0; j < 4; j++) acc[i][j] = (f32x4)0.f;
    for (int k0 = 0; k0 < 512; k0 += 32) {
        #pragma unroll
        for (int i = 0; i < 2; i++) {
            int s = i * 256 + tid;
            ASYNC16(y2 + (size_t)(m0 + (s >> 2)) * 512 + k0 + (s & 3) * 8, sm + s * 16);
        }
        #pragma unroll
        for (int i = 0; i < 2; i++) {
            int s = i * 256 + tid;
            ASYNC16(Bt + (size_t)(n0 + (s >> 2)) * 512 + k0 + (s & 3) * 8, sm + 8192 + s * 16);
        }
        __syncthreads();
        bf16x8 af[4], bfr[4];
        #pragma unroll
        for (int mf = 0; mf < 4; mf++)
            af[mf] = *(const bf16x8*)(sm + (wm * 64 + mf * 16 + lm) * 64 + q * 16);
        #pragma unroll
        for (int nf = 0; nf < 4; nf++)
            bfr[nf] = *(const bf16x8*)(sm + 8192 + (wn * 64 + nf * 16 + lm) * 64 + q * 16);
        #pragma unroll
        for (int mf = 0; mf < 4; mf++)
            #pragma unroll
            for (int nf = 0; nf < 4; nf++)
                acc[mf][nf] = __builtin_amdgcn_mfma_f32_16x16x32_bf16(af[mf], bfr[nf], acc[mf][nf], 0, 0, 0);
        __syncthreads();
    }
    #pragma unroll
    for (int mf = 0; mf < 4; mf++) {
        int mbase = m0 + wm * 64 + mf * 16 + q * 4;
        #pragma unroll
        for (int nf = 0; nf < 4; nf++) {
            int n = n0 + wn * 64 + nf * 16 + lm;
            #pragma unroll
            for (int r = 0; r < 4; r++) {
                size_t ci = (size_t)(mbase + r) * DMODEL + n;
                C[ci] += acc[mf][nf][r];
            }
        }
    }
}

// ---------------- elementwise norms ----------------
__global__ __launch_bounds__(256) void rmsnorm_all(
    const float* __restrict__ h, const float* __restrict__ wf,
    const float* __restrict__ wb, __bf16* __restrict__ u) {
    int row = blockIdx.x * 4 + (threadIdx.x >> 6);
    int lane = threadIdx.x & 63;
    const float* w = (row >= MFWD) ? wb : wf;
    float4 v = ((const float4*)(h + (size_t)row * 256))[lane];
    float ss = v.x * v.x + v.y * v.y + v.z * v.z + v.w * v.w;
    #pragma unroll
    for (int off = 32; off >= 1; off >>= 1) ss += __shfl_xor(ss, off);
    float rs = rsqrtf(ss * (1.f / 256.f) + 1e-5f);
    float4 wv = ((const float4*)w)[lane];
    __bf16 o4[4] = {(__bf16)(v.x * rs * wv.x), (__bf16)(v.y * rs * wv.y),
                    (__bf16)(v.z * rs * wv.z), (__bf16)(v.w * rs * wv.w)};
    *(uint2*)(u + (size_t)row * 256 + lane * 4) = *(uint2*)o4;
}

__global__ __launch_bounds__(256) void gatednorm_all(
    const __bf16* __restrict__ ysD, const __bf16* __restrict__ zxb,
    const float* __restrict__ gwf, const float* __restrict__ gwb,
    __bf16* __restrict__ y2) {
    int row = blockIdx.x * 4 + (threadIdx.x >> 6);
    int lane = threadIdx.x & 63;
    const float* gw = (row >= MFWD) ? gwb : gwf;
    union { uint4 u; __bf16 hh[8]; } yv, zv;
    yv.u = *(const uint4*)(ysD + (size_t)row * 512 + lane * 8);
    zv.u = *(const uint4*)(zxb + (size_t)row * ZXW + lane * 8);
    float g[8];
    #pragma unroll
    for (int j = 0; j < 8; j++) g[j] = (float)yv.hh[j] * silu_f((float)zv.hh[j]);
    float ss = 0.f;
    #pragma unroll
    for (int j = 0; j < 8; j++) ss += g[j] * g[j];
    #pragma unroll
    for (int off = 32; off >= 1; off >>= 1) ss += __shfl_xor(ss, off);
    float rs = rsqrtf(ss * (1.f / 512.f) + 1e-5f);
    const float4* gr = (const float4*)(gw + lane * 8);
    float4 g0 = gr[0], g1 = gr[1];
    union { uint4 u; __bf16 hh[8]; } d;
    d.hh[0] = (__bf16)(g[0] * rs * g0.x); d.hh[1] = (__bf16)(g[1] * rs * g0.y);
    d.hh[2] = (__bf16)(g[2] * rs * g0.z); d.hh[3] = (__bf16)(g[3] * rs * g0.w);
    d.hh[4] = (__bf16)(g[4] * rs * g1.x); d.hh[5] = (__bf16)(g[5] * rs * g1.y);
    d.hh[6] = (__bf16)(g[6] * rs * g1.z); d.hh[7] = (__bf16)(g[7] * rs * g1.w);
    *(uint4*)(y2 + (size_t)row * 512 + lane * 8) = d.u;
}

// ---------------- segmented prep kernel (all coalesced) ----------------
// WtT 256 | inprojT 1152 | outprojT 512 | poT 64 | WpreT 64 | dout 512 | im2row 192 | hinit 5120
__global__ void prep_all(const float* __restrict__ pre_conv_w, const float* __restrict__ patch_w,
                         const float* __restrict__ ip0, const float* __restrict__ ip1,
                         const float* __restrict__ op0, const float* __restrict__ op1,
                         const float* __restrict__ pow_, const float* __restrict__ pob,
                         const float* __restrict__ y_aux, const float* __restrict__ aux_w,
                         const float* __restrict__ aux_b, const float* __restrict__ xp,
                         const float* __restrict__ patch_b, const float* __restrict__ mtok,
                         __bf16* __restrict__ WpreT, __bf16* __restrict__ WtT,
                         __bf16* __restrict__ inprojT, __bf16* __restrict__ outprojT,
                         __bf16* __restrict__ poT, float* __restrict__ dout,
                         __bf16* __restrict__ Aim, float* __restrict__ h_all) {
    __shared__ float tile[32][33];
    int bx = blockIdx.x, tid = threadIdx.x;
    int tx = tid & 31, ty = tid >> 5;
    if (bx < 256) {
        int o = bx, c = tid;
        float f[16];
        const float4* s = (const float4*)(patch_w + (size_t)o * 4096 + c * 16);
        #pragma unroll
        for (int j = 0; j < 4; j++) *(float4*)&f[j * 4] = s[j];
        #pragma unroll
        for (int k = 0; k < 16; k++)
            WtT[(size_t)o * 4096 + k * 256 + c] = (__bf16)f[k];
        return;
    }
    bx -= 256;
    if (bx < 1152) {
        int seg = bx / 288, rem = bx % 288;
        int n0 = (rem / 8) * 32, k0 = (rem % 8) * 32;
        const float* src = (seg < 2 ? ip0 : ip1) + (size_t)(seg & 1) * 256 * DPROJ;
        #pragma unroll
        for (int j = 0; j < 4; j++) {
            int r = ty + j * 8;
            int n = n0 + tx;
            tile[r][tx] = (n < DPROJ) ? src[(size_t)(k0 + r) * DPROJ + n] : 0.f;
        }
        __syncthreads();
        __bf16* dst = inprojT + (size_t)seg * 1152 * 256;
        #pragma unroll
        for (int j = 0; j < 4; j++) {
            int r = ty + j * 8;
            dst[(size_t)(n0 + r) * 256 + k0 + tx] = (__bf16)tile[tx][r];
        }
        return;
    }
    bx -= 1152;
    if (bx < 512) {
        int s = bx / 128, rem = bx % 128;
        int n0 = (rem / 16) * 32, k0 = (rem % 16) * 32;
        const float* src = (s < 2 ? op0 : op1) + (size_t)(s & 1) * DINNER * DMODEL;
        #pragma unroll
        for (int j = 0; j < 4; j++) {
            int r = ty + j * 8;
            tile[r][tx] = src[(size_t)(k0 + r) * 256 + n0 + tx];
        }
        __syncthreads();
        __bf16* dst = outprojT + (size_t)s * 256 * 512;
        #pragma unroll
        for (int j = 0; j < 4; j++) {
            int r = ty + j * 8;
            dst[(size_t)(n0 + r) * 512 + k0 + tx] = (__bf16)tile[tx][r];
        }
        return;
    }
    bx -= 512;
    if (bx < 64) {
        int n0 = (bx / 16) * 32, k0 = (bx % 16) * 32;
        #pragma unroll
        for (int j = 0; j < 4; j++) {
            int r = ty + j * 8;
            tile[r][tx] = pow_[(size_t)(k0 + r) * 128 + n0 + tx];
        }
        __syncthreads();
        #pragma unroll
        for (int j = 0; j < 4; j++) {
            int r = ty + j * 8;
            poT[(size_t)(n0 + r) * 512 + k0 + tx] = (__bf16)tile[tx][r];
        }
        return;
    }
    bx -= 64;
    if (bx < 64) {
        int idx = bx * 256 + tid;
        int o = idx >> 6, kk = idx & 63;
        WpreT[idx] = (kk < 40) ? (__bf16)pre_conv_w[o * 40 + kk] : (__bf16)0.f;
        return;
    }
    bx -= 64;
    if (bx < 512) {
        int idx = bx * 256 + tid;
        dout[idx] = pob[idx & 127];
        return;
    }
    bx -= 512;
    if (bx < 192) {
        int m = bx * 256 + tid;
        int t = m % TPREF, b = m / TPREF;
        __bf16 d[64];
        #pragma unroll
        for (int k = 0; k < 5; k++) {
            int tt = t - 2 + k;
            bool ok = (tt >= 0) && (tt < TPREF);
            const float* s = xp + ((size_t)b * TPREF + tt) * 8;
            #pragma unroll
            for (int i = 0; i < 8; i++)
                d[i * 5 + k] = ok ? (__bf16)s[i] : (__bf16)0.f;
        }
        #pragma unroll
        for (int j = 40; j < 64; j++) d[j] = (__bf16)0.f;
        uint4* o = (uint4*)(Aim + (size_t)m * 64);
        #pragma unroll
        for (int k = 0; k < 8; k++) o[k] = ((const uint4*)d)[k];
        return;
    }
    bx -= 192;
    {   // h_all init: visible fwd rows = patch_b+aux (GEMM atomically adds patch term);
        // masked fwd rows and all bwd rows = mask_token+aux
        int row = bx, o = tid;
        int b; bool masked;
        if (row < MFWD) { b = row >> 9; int tok = row & 511; masked = (tok >= NVIS); }
        else { b = (row - MFWD) >> 7; masked = true; }
        float acc = aux_b[o];
        #pragma unroll
        for (int i = 0; i < 16; i++) acc += y_aux[b * 16 + i] * aux_w[i * 256 + o];
        float v = (masked ? mtok[o] : patch_b[o]) + silu_f(acc);
        h_all[(size_t)row * 256 + o] = v;
    }
}

// causal depthwise conv (k=4) + bias + silu; reads bf16 zxb. grid (9, 80)
__global__ __launch_bounds__(256) void dwconv2_kernel(
    const __bf16* __restrict__ zxb, const float* __restrict__ cwf, const float* __restrict__ cbf,
    const float* __restrict__ cwb, const float* __restrict__ cbb,
    __bf16* __restrict__ XtF, __bf16* __restrict__ XtB,
    __bf16* __restrict__ BCF, __bf16* __restrict__ BCB) {
    int cg = blockIdx.x;
    int id = blockIdx.y;
    int b, t0, T; size_t rowbase;
    const float *cw, *cb; __bf16 *Xt, *BC;
    if (id < 64) { b = id >> 3; t0 = (id & 7) * 64; T = NTOK; rowbase = (size_t)b * NTOK;
                   cw = cwf; cb = cbf; Xt = XtF; BC = BCF; }
    else { int i2 = id - 64; b = i2 >> 1; t0 = (i2 & 1) * 64; T = TBWD;
           rowbase = (size_t)MFWD + (size_t)b * TBWD; cw = cwb; cb = cbb; Xt = XtB; BC = BCB; }
    int c0 = cg * 64;
    __shared__ float xs[67][65];
    int lane = threadIdx.x & 63, grp = threadIdx.x >> 6;
    for (int r = grp; r < 67; r += 4) {
        int t = t0 - 3 + r;
        xs[r][lane] = (t >= 0) ? (float)zxb[(rowbase + t) * ZXW + DINNER + c0 + lane] : 0.f;
    }
    __syncthreads();
    if (cg < 8) {
        int t = lane;
        #pragma unroll
        for (int ci = grp; ci < 64; ci += 4) {
            int c = c0 + ci;
            float acc = cb[c];
            #pragma unroll
            for (int k = 0; k < 4; k++) acc += cw[c * 4 + k] * xs[t + k][ci];
            Xt[((size_t)((b * 8 + cg) * 64 + ci)) * T + t0 + t] = (__bf16)silu_f(acc);
        }
    } else {
        int c = lane;
        #pragma unroll
        for (int ti = grp; ti < 64; ti += 4) {
            float acc = cb[c0 + c];
            #pragma unroll
            for (int k = 0; k < 4; k++) acc += cw[(c0 + c) * 4 + k] * xs[ti + k][c];
            BC[((size_t)(b * T + t0 + ti)) * 64 + c] = (__bf16)silu_f(acc);
        }
    }
}

// ---------------- chunked SSD scan phase A. grid (80, 8) ----------------
__global__ __launch_bounds__(64) void scan_local(
    const __bf16* __restrict__ XtF, const __bf16* __restrict__ XtB,
    const __bf16* __restrict__ BCF, const __bf16* __restrict__ BCB,
    const float* __restrict__ dtc,
    const float* __restrict__ dtbf, const float* __restrict__ dtbb,
    const float* __restrict__ Alogf, const float* __restrict__ Alogb,
    const float* __restrict__ Dpf, const float* __restrict__ Dpb,
    __bf16* __restrict__ ysD,
    __bf16* __restrict__ ChatF, __bf16* __restrict__ ChatB,
    float* __restrict__ dSF, float* __restrict__ dSB,
    float* __restrict__ DcsF, float* __restrict__ DcsB, int layer) {
    int id = blockIdx.x, hd = blockIdx.y;
    int b, c, T, NC; size_t rowbase;
    const __bf16 *Xt, *BC; __bf16* Chat; float *dS, *Dcs;
    const float *dtb, *Alog, *Dp;
    if (id < 64) { b = id >> 3; c = id & 7; T = NTOK; NC = 8; rowbase = (size_t)b * NTOK;
                   Xt = XtF; BC = BCF; Chat = ChatF; dS = dSF; Dcs = DcsF;
                   dtb = dtbf; Alog = Alogf; Dp = Dpf; }
    else { int i2 = id - 64; b = i2 >> 1; c = i2 & 1; T = TBWD; NC = 2;
           rowbase = (size_t)MFWD + (size_t)b * TBWD;
           Xt = XtB; BC = BCB; Chat = ChatB; dS = dSB; Dcs = DcsB;
           dtb = dtbb; Alog = Alogb; Dp = Dpb; }
    bool skipY = (layer == 1) && (id < 64) && (c < 6);
    int bh = b * 8 + hd;
    int t0 = c * 64;
    int lane = threadIdx.x;
    int lm = lane & 15, q = lane >> 4;
    float A = -expf(Alog[hd]);
    float Dh = Dp[hd];

    __shared__ char smem[23552];
    __bf16 (*Xl)[72]  = (__bf16(*)[72])(smem);
    __bf16 (*BCl)[72] = (__bf16(*)[72])(smem + 9216);
    __bf16 (*Pl)[72]  = (__bf16(*)[72])(smem + 9216);
    __bf16 (*Wbl)[72] = (__bf16(*)[72])(smem + 18432);
    float* lcs = (float*)(smem + 23040);
    float* dts = (float*)(smem + 23296);

    const uint4* xg = (const uint4*)(Xt + (size_t)(bh * 64 + lane) * T + t0);
    const uint4* bg = (const uint4*)(BC + ((size_t)(b * T + t0 + lane)) * 64);
    uint4 xv[8], bv[8];
    #pragma unroll
    for (int k = 0; k < 8; k++) { xv[k] = xg[k]; bv[k] = bg[k]; }
    float xdt = dtc[(rowbase + t0 + lane) * 8 + hd] + dtb[hd];
    float dtv = (xdt > 20.f) ? xdt : log1pf(expf(xdt));
    #pragma unroll
    for (int k = 0; k < 8; k++) {
        *(uint4*)&Xl[lane][k * 8] = xv[k];
        if (!skipY) *(uint4*)&BCl[lane][k * 8] = bv[k];
    }
    float lc = A * dtv;
    #pragma unroll
    for (int off = 1; off < 64; off <<= 1) {
        float o = __shfl_up(lc, off);
        if (lane >= off) lc += o;
    }
    lcs[lane] = lc; dts[lane] = dtv;
    float lc63 = __shfl(lc, 63);
    float wj = expf(lc63 - lc) * dtv;
    float eli = expf(lc);
    float Dc = expf(lc63);
    if (lane == 0) Dcs[bh * NC + c] = Dc;
    if (!skipY) {
        __bf16* co = Chat + ((size_t)(bh * NC + c) * 64 + lane) * 32;
        #pragma unroll
        for (int k = 0; k < 4; k++) {
            union { uint4 u; __bf16 h[8]; } s; s.u = bv[4 + k];
            union { uint4 u; __bf16 h[8]; } d;
            #pragma unroll
            for (int j = 0; j < 8; j++) d.h[j] = (__bf16)(eli * (float)s.h[j]);
            *(uint4*)(co + k * 8) = d.u;
        }
    }
    #pragma unroll
    for (int k = 0; k < 4; k++) {
        union { uint4 u; __bf16 h[8]; } s; s.u = bv[k];
        #pragma unroll
        for (int j = 0; j < 8; j++) Wbl[k * 8 + j][lane] = (__bf16)(wj * (float)s.h[j]);
    }
    __syncthreads();

    bf16x8 xf0[4], xf1[4];
    if (!skipY) {
        bf16x8 cfr[4], bfr[4];
        #pragma unroll
        for (int t4 = 0; t4 < 4; t4++) {
            cfr[t4] = *(const bf16x8*)&BCl[t4 * 16 + lm][32 + q * 8];
            bfr[t4] = *(const bf16x8*)&BCl[t4 * 16 + lm][q * 8];
        }
        #pragma unroll
        for (int ti = 0; ti < 4; ti++) {
            float lci[4];
            #pragma unroll
            for (int r = 0; r < 4; r++) lci[r] = lcs[ti * 16 + q * 4 + r];
            #pragma unroll
            for (int tj = 0; tj < 4; tj++) {
                if (tj > ti) {
                    #pragma unroll
                    for (int r = 0; r < 4; r++) Pl[ti * 16 + q * 4 + r][tj * 16 + lm] = (__bf16)0.f;
                    continue;
                }
                f32x4 g = __builtin_amdgcn_mfma_f32_16x16x32_bf16(cfr[ti], bfr[tj], (f32x4)0.f, 0, 0, 0);
                int j = tj * 16 + lm;
                float lcj = lcs[j], dtj = dts[j];
                #pragma unroll
                for (int r = 0; r < 4; r++) {
                    int i = ti * 16 + q * 4 + r;
                    float v = (j <= i) ? g[r] * expf(lci[r] - lcj) * dtj : 0.f;
                    if (j == i) v += Dh;
                    Pl[i][j] = (__bf16)v;
                }
            }
        }
        __syncthreads();

        bf16x8 pf0[4], pf1[4];
        #pragma unroll
        for (int t4 = 0; t4 < 4; t4++) {
            pf0[t4] = *(const bf16x8*)&Pl[t4 * 16 + lm][q * 8];
            pf1[t4] = *(const bf16x8*)&Pl[t4 * 16 + lm][32 + q * 8];
            xf0[t4] = *(const bf16x8*)&Xl[t4 * 16 + lm][q * 8];
            xf1[t4] = *(const bf16x8*)&Xl[t4 * 16 + lm][32 + q * 8];
        }
        #pragma unroll
        for (int ti = 0; ti < 4; ti++) {
            #pragma unroll
            for (int tp = 0; tp < 4; tp++) {
                f32x4 y = __builtin_amdgcn_mfma_f32_16x16x32_bf16(pf0[ti], xf0[tp], (f32x4)0.f, 0, 0, 0);
                y = __builtin_amdgcn_mfma_f32_16x16x32_bf16(pf1[ti], xf1[tp], y, 0, 0, 0);
                #pragma unroll
                for (int r = 0; r < 4; r++) {
                    int i = ti * 16 + q * 4 + r;
                    ysD[(rowbase + t0 + i) * DINNER + hd * 64 + tp * 16 + lm] = (__bf16)y[r];
                }
            }
        }
    } else {
        #pragma unroll
        for (int t4 = 0; t4 < 4; t4++) {
            xf0[t4] = *(const bf16x8*)&Xl[t4 * 16 + lm][q * 8];
            xf1[t4] = *(const bf16x8*)&Xl[t4 * 16 + lm][32 + q * 8];
        }
    }
    bf16x8 wf0[2], wf1[2];
    #pragma unroll
    for (int tn = 0; tn < 2; tn++) {
        wf0[tn] = *(const bf16x8*)&Wbl[tn * 16 + lm][q * 8];
        wf1[tn] = *(const bf16x8*)&Wbl[tn * 16 + lm][32 + q * 8];
    }
    float* dso = dS + (size_t)(bh * NC + c) * 2048;
    #pragma unroll
    for (int tp = 0; tp < 4; tp++) {
        #pragma unroll
        for (int tn = 0; tn < 2; tn++) {
            f32x4 s = __builtin_amdgcn_mfma_f32_16x16x32_bf16(xf0[tp], wf0[tn], (f32x4)0.f, 0, 0, 0);
            s = __builtin_amdgcn_mfma_f32_16x16x32_bf16(xf1[tp], wf1[tn], s, 0, 0, 0);
            #pragma unroll
            for (int r = 0; r < 4; r++) {
                int pp = tp * 16 + q * 4 + r, nn = tn * 16 + lm;
                dso[pp * 32 + nn] = s[r];
            }
        }
    }
}

// ---------------- scan tail: recurrence + cross-chunk Y add ----------------
__global__ __launch_bounds__(256) void scan_tail(
    const float* __restrict__ dSF, const float* __restrict__ dSB,
    const float* __restrict__ DcsF, const float* __restrict__ DcsB,
    const __bf16* __restrict__ ChatF, const __bf16* __restrict__ ChatB,
    __bf16* __restrict__ ysD, int layer) {
    int blk = blockIdx.x;
    int dir = blk >= 64;
    int bh = blk & 63;
    int NC = dir ? 2 : 8;
    int T = dir ? TBWD : NTOK;
    int b = bh >> 3, hd = bh & 7;
    size_t rowbase = dir ? ((size_t)MFWD + (size_t)b * TBWD) : ((size_t)b * NTOK);
    const float* dS = dir ? dSB : dSF;
    const float* Dcs = dir ? DcsB : DcsF;
    const __bf16* Chat = dir ? ChatB : ChatF;
    int cmin = (layer == 1 && !dir) ? 6 : 1;
    int tid = threadIdx.x;
    __shared__ __bf16 Spl[8][64][40];
    {
        int p = tid >> 2, n0 = (tid & 3) * 8;
        float S[8];
        #pragma unroll
        for (int j = 0; j < 8; j++) S[j] = 0.f;
        for (int c = 0; c < NC; c++) {
            union { uint4 u; __bf16 hh[8]; } o;
            #pragma unroll
            for (int j = 0; j < 8; j++) o.hh[j] = (__bf16)S[j];
            *(uint4*)&Spl[c][p][n0] = o.u;
            float Dc = Dcs[bh * NC + c];
            const float4* dp = (const float4*)(dS + ((size_t)(bh * NC + c)) * 2048 + tid * 8);
            float4 d0 = dp[0], d1 = dp[1];
            S[0] = Dc * S[0] + d0.x; S[1] = Dc * S[1] + d0.y;
            S[2] = Dc * S[2] + d0.z; S[3] = Dc * S[3] + d0.w;
            S[4] = Dc * S[4] + d1.x; S[5] = Dc * S[5] + d1.y;
            S[6] = Dc * S[6] + d1.z; S[7] = Dc * S[7] + d1.w;
        }
    }
    __syncthreads();
    int w = tid >> 6, l = tid & 63, lm = l & 15, q = l >> 4;
    for (int c = cmin + w; c < NC; c += 4) {
        int t0 = c * 64;
        const __bf16* Cb = Chat + (size_t)(bh * NC + c) * 2048;
        bf16x8 cf[4], sf[4];
        #pragma unroll
        for (int t4 = 0; t4 < 4; t4++) {
            cf[t4] = *(const bf16x8*)(Cb + (t4 * 16 + lm) * 32 + q * 8);
            sf[t4] = *(const bf16x8*)&Spl[c][t4 * 16 + lm][q * 8];
        }
        #pragma unroll
        for (int ti = 0; ti < 4; ti++) {
            #pragma unroll
            for (int tp = 0; tp < 4; tp++) {
                f32x4 y = __builtin_amdgcn_mfma_f32_16x16x32_bf16(cf[ti], sf[tp], (f32x4)0.f, 0, 0, 0);
                #pragma unroll
                for (int r = 0; r < 4; r++) {
                    int i = ti * 16 + q * 4 + r;
                    size_t idx = (rowbase + t0 + i) * DINNER + hd * 64 + tp * 16 + lm;
                    ysD[idx] = (__bf16)((float)ysD[idx] + y[r]);
                }
            }
        }
    }
}

// ---------------- launch ----------------
extern "C" void kernel_launch(void* const* d_in, const int* in_sizes, int n_in,
                              void* d_out, int out_size, void* d_ws, size_t ws_size,
                              hipStream_t stream) {
    const float* x_prefix    = (const float*)d_in[0];
    const float* y_aux       = (const float*)d_in[1];
    const float* pre_conv_w  = (const float*)d_in[2];
    const float* pre_conv_b  = (const float*)d_in[3];
    const float* patch_w     = (const float*)d_in[4];
    const float* patch_b     = (const float*)d_in[5];
    const float* mask_token  = (const float*)d_in[6];
    const float* aux_w       = (const float*)d_in[7];
    const float* aux_b       = (const float*)d_in[8];
    const float* patch_out_w = (const float*)d_in[9];
    const float* patch_out_b = (const float*)d_in[10];
    const float* w_norm[2]   = {(const float*)d_in[11], (const float*)d_in[20]};
    const float* w_inproj[2] = {(const float*)d_in[12], (const float*)d_in[21]};
    const float* w_convw[2]  = {(const float*)d_in[13], (const float*)d_in[22]};
    const float* w_convb[2]  = {(const float*)d_in[14], (const float*)d_in[23]};
    const float* w_dtb[2]    = {(const float*)d_in[15], (const float*)d_in[24]};
    const float* w_alog[2]   = {(const float*)d_in[16], (const float*)d_in[25]};
    const float* w_D[2]      = {(const float*)d_in[17], (const float*)d_in[26]};
    const float* w_gnorm[2]  = {(const float*)d_in[18], (const float*)d_in[27]};
    const float* w_outproj[2]= {(const float*)d_in[19], (const float*)d_in[28]};

    char* p = (char*)d_ws;
    auto alloc = [&](size_t bytes) { char* r = p; p += (bytes + 255) & ~255ULL; return r; };
    __bf16* A_patch  = (__bf16*)alloc((size_t)3072 * 4096 * 2);
    __bf16* Aim      = (__bf16*)alloc((size_t)BSZ * TPREF * 64 * 2);
    __bf16* WpreT    = (__bf16*)alloc((size_t)256 * 64 * 2);
    __bf16* WtT      = (__bf16*)alloc((size_t)256 * 4096 * 2);
    __bf16* inprojT  = (__bf16*)alloc((size_t)4 * 1152 * 256 * 2);
    __bf16* outprojT = (__bf16*)alloc((size_t)4 * 256 * 512 * 2);
    __bf16* poT      = (__bf16*)alloc((size_t)128 * 512 * 2);
    float*  h_all    = (float*)alloc((size_t)MALL * 256 * 4);
    __bf16* u        = (__bf16*)alloc((size_t)MALL * 256 * 2);
    __bf16* zxb      = (__bf16*)alloc((size_t)MALL * ZXW * 2);
    float*  dtc      = (float*)alloc((size_t)MALL * 8 * 4);
    __bf16* XtF      = (__bf16*)alloc((size_t)64 * 64 * NTOK * 2);
    __bf16* XtB      = (__bf16*)alloc((size_t)64 * 64 * TBWD * 2);
    __bf16* BCF      = (__bf16*)alloc((size_t)BSZ * NTOK * 64 * 2);
    __bf16* BCB      = (__bf16*)alloc((size_t)BSZ * TBWD * 64 * 2);
    __bf16* ysD      = (__bf16*)alloc((size_t)MALL * DINNER * 2);
    __bf16* y2       = (__bf16*)alloc((size_t)MALL * DINNER * 2);
    __bf16* ChatF    = (__bf16*)alloc((size_t)64 * 8 * 2048 * 2);
    __bf16* ChatB    = (__bf16*)alloc((size_t)64 * 2 * 2048 * 2);
    float*  dSF      = (float*)alloc((size_t)64 * 8 * 2048 * 4);
    float*  dSB      = (float*)alloc((size_t)64 * 2 * 2048 * 4);
    float*  DcsF     = (float*)alloc((size_t)64 * 8 * 4);
    float*  DcsB     = (float*)alloc((size_t)64 * 2 * 4);

    // 1) prep: weights + im2row + d_out bias + h_all background (bias/mask + aux)
    prep_all<<<256 + 1152 + 512 + 64 + 64 + 512 + 192 + MALL, 256, 0, stream>>>(
        pre_conv_w, patch_w, w_inproj[0], w_inproj[1], w_outproj[0], w_outproj[1],
        patch_out_w, patch_out_b, y_aux, aux_w, aux_b, x_prefix, patch_b, mask_token,
        WpreT, WtT, inprojT, outprojT, poT, (float*)d_out, Aim, h_all);
    // 2) pre-conv GEMM (silu+bf16 -> A_patch)
    gemm_mfma<<<dim3(2, (BSZ * TPREF) / 128, 1), 256, 0, stream>>>(
        Aim, WpreT, (float*)A_patch, pre_conv_b, 256, 64, 256, 4);
    // 3) patch GEMM: split-K 8, atomicAdd into pre-initialized h_all (row remap)
    gemm_mfma<<<dim3(2, 24, 8), 256, 0, stream>>>(
        A_patch, WtT, h_all, nullptr, 256, 4096, 256, 16);

    for (int i = 0; i < 2; i++) {
        const __bf16* ipTf = inprojT + (size_t)(0 * 2 + i) * 1152 * 256;
        const __bf16* ipTb = inprojT + (size_t)(1 * 2 + i) * 1152 * 256;
        const __bf16* opTf = outprojT + (size_t)(0 * 2 + i) * 256 * 512;
        const __bf16* opTb = outprojT + (size_t)(1 * 2 + i) * 256 * 512;
        rmsnorm_all<<<MALL / 4, 256, 0, stream>>>(h_all, w_norm[0] + i * 256, w_norm[1] + i * 256, u);
        gemm_inproj<<<dim3(9, MALL / 128), 256, 0, stream>>>(u, ipTf, ipTb, zxb, dtc);
        dwconv2_kernel<<<dim3(9, 80), 256, 0, stream>>>(
            zxb, w_convw[0] + i * CONVDIM * 4, w_convb[0] + i * CONVDIM,
            w_convw[1] + i * CONVDIM * 4, w_convb[1] + i * CONVDIM,
            XtF, XtB, BCF, BCB);
        scan_local<<<dim3(80, NHEADS), 64, 0, stream>>>(
            XtF, XtB, BCF, BCB, dtc,
            w_dtb[0] + i * 8, w_dtb[1] + i * 8,
            w_alog[0] + i * 8, w_alog[1] + i * 8,
            w_D[0] + i * 8, w_D[1] + i * 8,
            ysD, ChatF, ChatB, dSF, dSB, DcsF, DcsB, i);
        scan_tail<<<128, 256, 0, stream>>>(dSF, dSB, DcsF, DcsB, ChatF, ChatB, ysD, i);
        gatednorm_all<<<MALL / 4, 256, 0, stream>>>(
            ysD, zxb, w_gnorm[0] + i * DINNER, w_gnorm[1] + i * DINNER, y2);
        int oy = (i == 0) ? (MALL / 128) : 16;
        gemm_outproj<<<dim3(2, oy), 256, 0, stream>>>(y2, opTf, opTb, h_all, i);
    }

    // final: fused hcat gather + patch_out GEMM, atomic into bias-initialized d_out
    final_gemm<<<dim3(1, 8, 2), 256, 0, stream>>>(h_all, poT, (float*)d_out);
}